// Round 1
// baseline (448.767 us; speedup 1.0000x reference)
//
#include <hip/hip_runtime.h>
#include <hip/hip_bf16.h>

typedef __bf16 bf16x8 __attribute__((ext_vector_type(8)));
typedef float f32x4 __attribute__((ext_vector_type(4)));
typedef unsigned int uint;
typedef unsigned short u16;

#define DEV static __device__ __forceinline__

DEV u16 f2bf(float x) {
    uint u = __builtin_bit_cast(uint, x);
    u += 0x7FFFu + ((u >> 16) & 1u);
    return (u16)(u >> 16);
}

DEV void gload16(const void* g, void* l) {
    __builtin_amdgcn_global_load_lds((const __attribute__((address_space(1))) void*)g,
                                     (__attribute__((address_space(3))) void*)l,
                                     16, 0, 0);
}

// ---------------- fp32 -> bf16 conversion (vectorized, 8 elem/thread) --------
__global__ __launch_bounds__(256) void k_f32_to_bf16(const float* __restrict__ in,
                                                     u16* __restrict__ out, int n8) {
    int i = blockIdx.x * 256 + threadIdx.x;
    if (i >= n8) return;
    const float4* p = (const float4*)in + (long)i * 2;
    float4 a = p[0], b = p[1];
    u16 r[8];
    r[0] = f2bf(a.x); r[1] = f2bf(a.y); r[2] = f2bf(a.z); r[3] = f2bf(a.w);
    r[4] = f2bf(b.x); r[5] = f2bf(b.y); r[6] = f2bf(b.z); r[7] = f2bf(b.w);
    ((uint4*)out)[i] = *(const uint4*)r;
}

// ---------------- bf16 GEMM, C = A * Bw^T + bias ----------------------------
// A: [M][K] row-major bf16.  Bw: [N][K] row-major bf16 (torch Linear weight).
// 128x128 tile, BK=64, 4 waves (2x2), 16x16x32 MFMA. m97 structure:
// global_load_lds(16B) with pre-swizzled source + swizzled ds_read (rule #21).
template <int OUTF32>
__global__ __launch_bounds__(256, 2) void k_gemm_bt(
    const u16* __restrict__ A, const u16* __restrict__ Bw,
    const float* __restrict__ bias, float* __restrict__ Cf, u16* __restrict__ Cb,
    int M, int N, int K) {
    __shared__ u16 lA[128 * 64];
    __shared__ u16 lB[128 * 64];
    const int tid = threadIdx.x;
    const int l = tid & 63, w = tid >> 6;
    const int lr = l & 15, lk = l >> 4;
    const int wr = w >> 1, wc = w & 1;
    const int nbn = N >> 7;
    const int bm = blockIdx.x / nbn, bn = blockIdx.x % nbn;

    // staging precompute: chunk c covers LDS bytes [c*16, c*16+16)
    long abase[4], bbase[4];
    int ldst[4];
#pragma unroll
    for (int t = 0; t < 4; ++t) {
        int c = t * 256 + tid;
        int p = c * 16;
        int row = p >> 7;          // 128 B per row (64 bf16)
        int inrow = p & 127;
        int src = inrow ^ ((row & 7) << 4);   // inverse-swizzled source
        ldst[t] = p;
        abase[t] = (long)(bm * 128 + row) * (K * 2) + src;
        bbase[t] = (long)(bn * 128 + row) * (K * 2) + src;
    }
    const int swz = (lr & 7) << 4;
    int aoff[4][2], boff[4][2];
#pragma unroll
    for (int m = 0; m < 4; ++m)
#pragma unroll
        for (int kc = 0; kc < 2; ++kc) {
            aoff[m][kc] = (wr * 64 + m * 16 + lr) * 128 + ((kc * 64 + lk * 16) ^ swz);
            boff[m][kc] = (wc * 64 + m * 16 + lr) * 128 + ((kc * 64 + lk * 16) ^ swz);
        }

    f32x4 acc[4][4] = {};
    const char* gA = (const char*)A;
    const char* gB = (const char*)Bw;
    const char* lAb = (const char*)lA;
    const char* lBb = (const char*)lB;
    const int nkt = K >> 6;
    for (int kt = 0; kt < nkt; ++kt) {
        __syncthreads();
#pragma unroll
        for (int t = 0; t < 4; ++t)
            gload16(gA + abase[t] + kt * 128, (char*)lA + ldst[t]);
#pragma unroll
        for (int t = 0; t < 4; ++t)
            gload16(gB + bbase[t] + kt * 128, (char*)lB + ldst[t]);
        __syncthreads();
#pragma unroll
        for (int kc = 0; kc < 2; ++kc) {
            bf16x8 av[4], bv[4];
#pragma unroll
            for (int m = 0; m < 4; ++m) av[m] = *(const bf16x8*)(lAb + aoff[m][kc]);
#pragma unroll
            for (int n = 0; n < 4; ++n) bv[n] = *(const bf16x8*)(lBb + boff[n][kc]);
#pragma unroll
            for (int m = 0; m < 4; ++m)
#pragma unroll
                for (int n = 0; n < 4; ++n)
                    acc[m][n] = __builtin_amdgcn_mfma_f32_16x16x32_bf16(av[m], bv[n], acc[m][n], 0, 0, 0);
        }
    }

    // epilogue: C row = (lk*4+j), col = lr within each 16x16 fragment
    const int row0 = bm * 128 + wr * 64;
    const int col0 = bn * 128 + wc * 64;
    float bval[4];
#pragma unroll
    for (int n = 0; n < 4; ++n) bval[n] = bias[col0 + n * 16 + lr];
#pragma unroll
    for (int m = 0; m < 4; ++m)
#pragma unroll
        for (int j = 0; j < 4; ++j) {
            int row = row0 + m * 16 + lk * 4 + j;
#pragma unroll
            for (int n = 0; n < 4; ++n) {
                float v = acc[m][n][j] + bval[n];
                int col = col0 + n * 16 + lr;
                if (OUTF32) Cf[(long)row * N + col] = v;
                else        Cb[(long)row * N + col] = f2bf(v);
            }
        }
}

// ---------------- flash attention, bf16, per (b,h) --------------------------
// 4 waves/block, 32 Q-rows/wave (128 rows/block), KV tile = 64.
__global__ __launch_bounds__(256, 2) void k_attn(
    const u16* __restrict__ Qb, const u16* __restrict__ Kb,
    const u16* __restrict__ Vb, u16* __restrict__ Ob) {
    constexpr int T = 2048, D = 1024;
    __shared__ u16 lK[64 * 64];      // [k][d], swizzled
    __shared__ u16 lV[64 * 64];      // V^T: [d][k], swizzled
    __shared__ u16 lP[4][32 * 64];   // per-wave P, swizzled
    const int tid = threadIdx.x;
    const int l = tid & 63, w = tid >> 6;
    const int lr = l & 15, lk = l >> 4;
    const int swz = (lr & 7) << 4;
    const int qt = blockIdx.x & 15;
    const int bh = blockIdx.x >> 4;
    const int b = bh >> 4, h = bh & 15;

    const char* Qg = (const char*)(Qb + (long)b * T * D + h * 64);
    const char* Kg = (const char*)(Kb + (long)b * T * D + h * 64);
    const char* Vg = (const char*)(Vb + (long)b * T * D + h * 64);

    const int q0 = qt * 128 + w * 32;

    // Q fragments direct from global (one-time)
    bf16x8 qf[2][2];
#pragma unroll
    for (int m = 0; m < 2; ++m)
#pragma unroll
        for (int kc = 0; kc < 2; ++kc)
            qf[m][kc] = *(const bf16x8*)(Qg + (long)(q0 + m * 16 + lr) * 2048 + kc * 64 + lk * 16);

    // K staging precompute (2 x 16B chunks per thread, swizzled source)
    long kbase[2];
    int kdst[2];
#pragma unroll
    for (int t = 0; t < 2; ++t) {
        int p = (t * 256 + tid) * 16;
        int row = p >> 7;
        int src = (p & 127) ^ ((row & 7) << 4);
        kdst[t] = p;
        kbase[t] = (long)row * 2048 + src;
    }
    const int kr = tid >> 2;            // V staging: k-row
    const int dq = (tid & 3) * 16;      // d block of 16

    f32x4 oacc[2][4] = {};
    float mrun[2][4], lrun[2][4];
#pragma unroll
    for (int m = 0; m < 2; ++m)
#pragma unroll
        for (int j = 0; j < 4; ++j) { mrun[m][j] = -1e30f; lrun[m][j] = 0.f; }

    char* lKb = (char*)lK;
    char* lVb = (char*)lV;
    char* lPw = (char*)lP[w];

    for (int kt = 0; kt < T / 64; ++kt) {
        __syncthreads();
        // stage K tile via global_load_lds
#pragma unroll
        for (int t = 0; t < 2; ++t)
            gload16(Kg + (long)kt * 64 * 2048 + kbase[t], (char*)lK + kdst[t]);
        // reg-stage V transposed: V^T[d][k], swizzled per-row (d)
        u16 vreg[16];
        const char* vsrc = Vg + (long)(kt * 64 + kr) * 2048 + dq * 2;
        *(uint4*)&vreg[0] = *(const uint4*)vsrc;
        *(uint4*)&vreg[8] = *(const uint4*)(vsrc + 16);
#pragma unroll
        for (int ii = 0; ii < 16; ++ii) {
            int i = (ii + kr) & 15;     // permuted order to spread banks
            int d = dq + i;
            *(u16*)(lVb + d * 128 + ((kr * 2) ^ ((d & 7) << 4))) = vreg[i];
        }
        __syncthreads();

        // S = Q K^T  (rows = q, cols = kv)
        f32x4 sacc[2][4] = {};
#pragma unroll
        for (int kc = 0; kc < 2; ++kc) {
            bf16x8 kf[4];
#pragma unroll
            for (int n = 0; n < 4; ++n)
                kf[n] = *(const bf16x8*)(lKb + (n * 16 + lr) * 128 + ((kc * 64 + lk * 16) ^ swz));
#pragma unroll
            for (int m = 0; m < 2; ++m)
#pragma unroll
                for (int n = 0; n < 4; ++n)
                    sacc[m][n] = __builtin_amdgcn_mfma_f32_16x16x32_bf16(qf[m][kc], kf[n], sacc[m][n], 0, 0, 0);
        }

        // online softmax; row = m*16 + lk*4 + j; row-reduce over low-4 lane bits
#pragma unroll
        for (int m = 0; m < 2; ++m)
#pragma unroll
            for (int j = 0; j < 4; ++j) {
                float rm = sacc[m][0][j];
#pragma unroll
                for (int n = 1; n < 4; ++n) rm = fmaxf(rm, sacc[m][n][j]);
                rm = fmaxf(rm, __shfl_xor(rm, 1));
                rm = fmaxf(rm, __shfl_xor(rm, 2));
                rm = fmaxf(rm, __shfl_xor(rm, 4));
                rm = fmaxf(rm, __shfl_xor(rm, 8));
                rm *= 0.125f;
                float mn = fmaxf(mrun[m][j], rm);
                float alpha = exp2f((mrun[m][j] - mn) * 1.44269504f);
                mrun[m][j] = mn;
                float ls = 0.f;
#pragma unroll
                for (int n = 0; n < 4; ++n) {
                    float p = exp2f((sacc[m][n][j] * 0.125f - mn) * 1.44269504f);
                    sacc[m][n][j] = p;
                    ls += p;
                }
                ls += __shfl_xor(ls, 1);
                ls += __shfl_xor(ls, 2);
                ls += __shfl_xor(ls, 4);
                ls += __shfl_xor(ls, 8);
                lrun[m][j] = lrun[m][j] * alpha + ls;
#pragma unroll
                for (int n = 0; n < 4; ++n) oacc[m][n][j] *= alpha;
            }

        // write P (bf16) into wave-private swizzled LDS
#pragma unroll
        for (int m = 0; m < 2; ++m)
#pragma unroll
            for (int j = 0; j < 4; ++j) {
                int row = m * 16 + lk * 4 + j;
                int rs = (row & 7) << 4;
#pragma unroll
                for (int n = 0; n < 4; ++n)
                    *(u16*)(lPw + row * 128 + (((n * 16 + lr) * 2) ^ rs)) = f2bf(sacc[m][n][j]);
            }

        // O += P * V
#pragma unroll
        for (int kc = 0; kc < 2; ++kc) {
            bf16x8 vf[4], pf[2];
#pragma unroll
            for (int n = 0; n < 4; ++n)
                vf[n] = *(const bf16x8*)(lVb + (n * 16 + lr) * 128 + ((kc * 64 + lk * 16) ^ swz));
#pragma unroll
            for (int m = 0; m < 2; ++m)
                pf[m] = *(const bf16x8*)(lPw + (m * 16 + lr) * 128 + ((kc * 64 + lk * 16) ^ swz));
#pragma unroll
            for (int m = 0; m < 2; ++m)
#pragma unroll
                for (int n = 0; n < 4; ++n)
                    oacc[m][n] = __builtin_amdgcn_mfma_f32_16x16x32_bf16(pf[m], vf[n], oacc[m][n], 0, 0, 0);
        }
    }

    // epilogue: O /= l, write bf16
#pragma unroll
    for (int m = 0; m < 2; ++m)
#pragma unroll
        for (int j = 0; j < 4; ++j) {
            float inv = 1.f / lrun[m][j];
            int trow = q0 + m * 16 + lk * 4 + j;
            char* orow = (char*)Ob + ((long)(b * T + trow) * D + h * 64) * 2;
#pragma unroll
            for (int n = 0; n < 4; ++n)
                *(u16*)(orow + (n * 16 + lr) * 2) = f2bf(oacc[m][n][j] * inv);
        }
}

// ---------------------------------------------------------------------------
extern "C" void kernel_launch(void* const* d_in, const int* in_sizes, int n_in,
                              void* d_out, int out_size, void* d_ws, size_t ws_size,
                              hipStream_t stream) {
    const float* q  = (const float*)d_in[0];
    const float* k  = (const float*)d_in[1];
    const float* v  = (const float*)d_in[2];
    const float* Wq = (const float*)d_in[3];
    const float* bq = (const float*)d_in[4];
    const float* Wk = (const float*)d_in[5];
    const float* bk = (const float*)d_in[6];
    const float* Wv = (const float*)d_in[7];
    const float* bv = (const float*)d_in[8];
    const float* Wo = (const float*)d_in[9];
    const float* bo = (const float*)d_in[10];

    const long MT = 8192L * 1024;   // activation elems
    const long WT = 1024L * 1024;   // weight elems
    u16* ws  = (u16*)d_ws;
    u16* wqb = ws;
    u16* wkb = wqb + WT;
    u16* wvb = wkb + WT;
    u16* wob = wvb + WT;
    u16* xb  = wob + WT;
    u16* qbf = xb + MT;
    u16* kbf = qbf + MT;
    u16* vbf = kbf + MT;
    u16* abf = vbf + MT;

    dim3 blk(256);
    // weight conversions
    k_f32_to_bf16<<<dim3(512), blk, 0, stream>>>(Wq, wqb, (int)(WT / 8));
    k_f32_to_bf16<<<dim3(512), blk, 0, stream>>>(Wk, wkb, (int)(WT / 8));
    k_f32_to_bf16<<<dim3(512), blk, 0, stream>>>(Wv, wvb, (int)(WT / 8));
    k_f32_to_bf16<<<dim3(512), blk, 0, stream>>>(Wo, wob, (int)(WT / 8));

    dim3 ggrid(512);  // (8192/128) * (1024/128)
    k_f32_to_bf16<<<dim3(4096), blk, 0, stream>>>(q, xb, (int)(MT / 8));
    k_gemm_bt<0><<<ggrid, blk, 0, stream>>>(xb, wqb, bq, nullptr, qbf, 8192, 1024, 1024);
    k_f32_to_bf16<<<dim3(4096), blk, 0, stream>>>(k, xb, (int)(MT / 8));
    k_gemm_bt<0><<<ggrid, blk, 0, stream>>>(xb, wkb, bk, nullptr, kbf, 8192, 1024, 1024);
    k_f32_to_bf16<<<dim3(4096), blk, 0, stream>>>(v, xb, (int)(MT / 8));
    k_gemm_bt<0><<<ggrid, blk, 0, stream>>>(xb, wvb, bv, nullptr, vbf, 8192, 1024, 1024);

    k_attn<<<dim3(1024), blk, 0, stream>>>(qbf, kbf, vbf, abf);

    k_gemm_bt<1><<<ggrid, blk, 0, stream>>>(abf, wob, bo, (float*)d_out, nullptr, 8192, 1024, 1024);
}

// Round 2
// 274.261 us; speedup vs baseline: 1.6363x; 1.6363x over previous
//
#include <hip/hip_runtime.h>
#include <hip/hip_bf16.h>

typedef __bf16 bf16x8 __attribute__((ext_vector_type(8)));
typedef float f32x4 __attribute__((ext_vector_type(4)));
typedef float f32x16 __attribute__((ext_vector_type(16)));
typedef unsigned int uint;
typedef unsigned short u16;

#define DEV static __device__ __forceinline__

DEV u16 f2bf(float x) {
    uint u = __builtin_bit_cast(uint, x);
    u += 0x7FFFu + ((u >> 16) & 1u);
    return (u16)(u >> 16);
}

DEV uint cvtpk(float lo, float hi) {
    uint r;
    asm("v_cvt_pk_bf16_f32 %0, %1, %2" : "=v"(r) : "v"(lo), "v"(hi));
    return r;
}

DEV void plswap(uint& a, uint& b) {
    asm("v_permlane32_swap_b32 %0, %1" : "+v"(a), "+v"(b));
}

DEV void gload16(const void* g, void* l) {
    __builtin_amdgcn_global_load_lds((const __attribute__((address_space(1))) void*)g,
                                     (__attribute__((address_space(3))) void*)l,
                                     16, 0, 0);
}

// ---------------- fp32 -> bf16 conversion (vectorized, 8 elem/thread) --------
__global__ __launch_bounds__(256) void k_f32_to_bf16(const float* __restrict__ in,
                                                     u16* __restrict__ out, int n8) {
    int i = blockIdx.x * 256 + threadIdx.x;
    if (i >= n8) return;
    const float4* p = (const float4*)in + (long)i * 2;
    float4 a = p[0], b = p[1];
    u16 r[8];
    r[0] = f2bf(a.x); r[1] = f2bf(a.y); r[2] = f2bf(a.z); r[3] = f2bf(a.w);
    r[4] = f2bf(b.x); r[5] = f2bf(b.y); r[6] = f2bf(b.z); r[7] = f2bf(b.w);
    ((uint4*)out)[i] = *(const uint4*)r;
}

// ---------------- bf16 GEMM, C = A * Bw^T + bias ----------------------------
template <int OUTF32>
__global__ __launch_bounds__(256, 2) void k_gemm_bt(
    const u16* __restrict__ A, const u16* __restrict__ Bw,
    const float* __restrict__ bias, float* __restrict__ Cf, u16* __restrict__ Cb,
    int M, int N, int K) {
    __shared__ u16 lA[128 * 64];
    __shared__ u16 lB[128 * 64];
    const int tid = threadIdx.x;
    const int l = tid & 63, w = tid >> 6;
    const int lr = l & 15, lk = l >> 4;
    const int wr = w >> 1, wc = w & 1;
    const int nbn = N >> 7;
    const int bm = blockIdx.x / nbn, bn = blockIdx.x % nbn;

    long abase[4], bbase[4];
    int ldst[4];
#pragma unroll
    for (int t = 0; t < 4; ++t) {
        int c = t * 256 + tid;
        int p = c * 16;
        int row = p >> 7;
        int inrow = p & 127;
        int src = inrow ^ ((row & 7) << 4);
        ldst[t] = p;
        abase[t] = (long)(bm * 128 + row) * (K * 2) + src;
        bbase[t] = (long)(bn * 128 + row) * (K * 2) + src;
    }
    const int swz = (lr & 7) << 4;
    int aoff[4][2], boff[4][2];
#pragma unroll
    for (int m = 0; m < 4; ++m)
#pragma unroll
        for (int kc = 0; kc < 2; ++kc) {
            aoff[m][kc] = (wr * 64 + m * 16 + lr) * 128 + ((kc * 64 + lk * 16) ^ swz);
            boff[m][kc] = (wc * 64 + m * 16 + lr) * 128 + ((kc * 64 + lk * 16) ^ swz);
        }

    f32x4 acc[4][4] = {};
    const char* gA = (const char*)A;
    const char* gB = (const char*)Bw;
    const char* lAb = (const char*)lA;
    const char* lBb = (const char*)lB;
    const int nkt = K >> 6;
    for (int kt = 0; kt < nkt; ++kt) {
        __syncthreads();
#pragma unroll
        for (int t = 0; t < 4; ++t)
            gload16(gA + abase[t] + kt * 128, (char*)lA + ldst[t]);
#pragma unroll
        for (int t = 0; t < 4; ++t)
            gload16(gB + bbase[t] + kt * 128, (char*)lB + ldst[t]);
        __syncthreads();
#pragma unroll
        for (int kc = 0; kc < 2; ++kc) {
            bf16x8 av[4], bv[4];
#pragma unroll
            for (int m = 0; m < 4; ++m) av[m] = *(const bf16x8*)(lAb + aoff[m][kc]);
#pragma unroll
            for (int n = 0; n < 4; ++n) bv[n] = *(const bf16x8*)(lBb + boff[n][kc]);
#pragma unroll
            for (int m = 0; m < 4; ++m)
#pragma unroll
                for (int n = 0; n < 4; ++n)
                    acc[m][n] = __builtin_amdgcn_mfma_f32_16x16x32_bf16(av[m], bv[n], acc[m][n], 0, 0, 0);
        }
    }

    const int row0 = bm * 128 + wr * 64;
    const int col0 = bn * 128 + wc * 64;
    float bval[4];
#pragma unroll
    for (int n = 0; n < 4; ++n) bval[n] = bias[col0 + n * 16 + lr];
#pragma unroll
    for (int m = 0; m < 4; ++m)
#pragma unroll
        for (int j = 0; j < 4; ++j) {
            int row = row0 + m * 16 + lk * 4 + j;
#pragma unroll
            for (int n = 0; n < 4; ++n) {
                float v = acc[m][n][j] + bval[n];
                int col = col0 + n * 16 + lr;
                if (OUTF32) Cf[(long)row * N + col] = v;
                else        Cb[(long)row * N + col] = f2bf(v);
            }
        }
}

// ---------------- flash attention v2: 8 waves, 32x32 MFMA, swapped QK^T ------
// per block: 256 q rows (32/wave), KV tile 64, per (b,h): grid 64*8
__global__ __launch_bounds__(512, 4) void k_attn2(
    const u16* __restrict__ Qb, const u16* __restrict__ Kb,
    const u16* __restrict__ Vb, u16* __restrict__ Ob) {
    constexpr int T = 2048, D = 1024;
    __shared__ u16 sK[2][64 * 64];   // [buf][kv][d], XOR-swizzled rows
    __shared__ u16 sVT[64 * 64];     // V^T [d][kv], double-XOR-swizzled rows
    const int tid = threadIdx.x;
    const int l = tid & 63, w = tid >> 6;
    const int hi = l >> 5;
    const int q32 = l & 31;
    const int hi16 = hi * 16;
    const int kswz = (q32 & 7) << 4;
    const int sw0 = (q32 & 7) ^ ((q32 >> 3) & 7);        // VT swizzle, rows 0-31
    const int sw1 = sw0 ^ 4;                              // VT swizzle, rows 32-63
    const int qt = blockIdx.x & 7;
    const int bh = blockIdx.x >> 3;
    const int b = bh >> 4, h = bh & 15;

    const char* Qg = (const char*)(Qb + (long)b * T * D + h * 64);
    const char* Kg = (const char*)(Kb + (long)b * T * D + h * 64);
    const char* Vg = (const char*)(Vb + (long)b * T * D + h * 64);
    const int q0 = qt * 256 + w * 32;

    // Q fragments (B-operand rows = q, k = d): lane holds q = q0+q32, d = c*16+hi*8+j
    bf16x8 qf[4];
#pragma unroll
    for (int c = 0; c < 4; ++c)
        qf[c] = *(const bf16x8*)(Qg + (long)(q0 + q32) * 2048 + c * 32 + hi16);

    // K staging: 512 threads x 16B = 8KB tile; linear LDS dst, pre-swizzled src
    const int krow = tid >> 3;
    const int ksrc = ((tid & 7) * 16) ^ ((krow & 7) << 4);
    const int kdst = tid * 16;

    // V staging: lane loads V[kv = w*8 + (l>>3)][d0 = (l&7)*8 .. +7]
    const int vr = l >> 3;
    const int vdb = l & 7;
    const int vkv = w * 8 + vr;
    const int vd0 = vdb * 8;
    const int vtd = vd0 + vr;        // V^T row this lane writes post-transpose
    char* vtw = (char*)sVT + vtd * 128 +
                (((w ^ (vtd & 7) ^ ((vtd >> 3) & 7)) & 7) << 4);

    // prologue: stage tile 0
    gload16(Kg + (long)krow * 2048 + ksrc, (char*)sK[0] + kdst);
    uint4 vd = *(const uint4*)(Vg + (long)vkv * 2048 + vd0 * 2);

    f32x16 o[2] = {};
    float m = -1e30f, lsum = 0.f;
    const float k1 = 0.18033688f;        // 0.125 * log2(e)
    const float THR = 8.0f / 0.18033688f;

    for (int kt = 0; kt < T / 64; ++kt) {
        __syncthreads();   // A: prev compute done; staged loads drained

        // in-register 8x8 u16 transpose among lanes (bits 3,4,5), then b128 write
        uint w0 = vd.x, w1 = vd.y, w2 = vd.z, w3 = vd.w;
        {   // lane bit 5 <-> elem bit 2
            int lam = (l >> 5) & 1;
            uint s0 = lam ? w0 : w2, s1 = lam ? w1 : w3;
            uint t0 = __shfl_xor(s0, 32), t1 = __shfl_xor(s1, 32);
            if (lam) { w0 = t0; w1 = t1; } else { w2 = t0; w3 = t1; }
        }
        {   // lane bit 4 <-> elem bit 1
            int lam = (l >> 4) & 1;
            uint s0 = lam ? w0 : w1, s1 = lam ? w2 : w3;
            uint t0 = __shfl_xor(s0, 16), t1 = __shfl_xor(s1, 16);
            if (lam) { w0 = t0; w2 = t1; } else { w1 = t0; w3 = t1; }
        }
        {   // lane bit 3 <-> elem bit 0 (u16 within dwords)
            int lam = (l >> 3) & 1;
            uint sA = lam ? ((w0 & 0xFFFFu) | (w1 << 16)) : ((w0 >> 16) | (w1 & 0xFFFF0000u));
            uint sB = lam ? ((w2 & 0xFFFFu) | (w3 << 16)) : ((w2 >> 16) | (w3 & 0xFFFF0000u));
            uint tA = __shfl_xor(sA, 8), tB = __shfl_xor(sB, 8);
            if (lam) {
                w0 = (w0 & 0xFFFF0000u) | (tA & 0xFFFFu);
                w1 = (w1 & 0xFFFF0000u) | (tA >> 16);
                w2 = (w2 & 0xFFFF0000u) | (tB & 0xFFFFu);
                w3 = (w3 & 0xFFFF0000u) | (tB >> 16);
            } else {
                w0 = (w0 & 0xFFFFu) | (tA << 16);
                w1 = (w1 & 0xFFFFu) | (tA & 0xFFFF0000u);
                w2 = (w2 & 0xFFFFu) | (tB << 16);
                w3 = (w3 & 0xFFFFu) | (tB & 0xFFFF0000u);
            }
        }
        *(uint4*)vtw = make_uint4(w0, w1, w2, w3);
        __syncthreads();   // B: V^T visible; K[kt&1] staged since last iter

        // prefetch next tile (latency hidden under compute below)
        if (kt < T / 64 - 1) {
            gload16(Kg + (long)((kt + 1) * 64 + krow) * 2048 + ksrc,
                    (char*)sK[(kt + 1) & 1] + kdst);
            vd = *(const uint4*)(Vg + (long)((kt + 1) * 64 + vkv) * 2048 + vd0 * 2);
        }

        // S^T = mfma(K, Q): col = q (lane), rows = kv (regs)
        const char* kbp = (const char*)sK[kt & 1];
        f32x16 st[2] = {};
#pragma unroll
        for (int c = 0; c < 4; ++c) {
            bf16x8 kf = *(const bf16x8*)(kbp + q32 * 128 + ((c * 32 + hi16) ^ kswz));
            st[0] = __builtin_amdgcn_mfma_f32_32x32x16_bf16(kf, qf[c], st[0], 0, 0, 0);
        }
#pragma unroll
        for (int c = 0; c < 4; ++c) {
            bf16x8 kf = *(const bf16x8*)(kbp + (32 + q32) * 128 + ((c * 32 + hi16) ^ kswz));
            st[1] = __builtin_amdgcn_mfma_f32_32x32x16_bf16(kf, qf[c], st[1], 0, 0, 0);
        }

        // in-register online softmax (lane owns q-row = q32; partner l^32 has other 32 kv)
        float rm = st[0][0];
#pragma unroll
        for (int r = 1; r < 16; ++r) rm = fmaxf(rm, st[0][r]);
#pragma unroll
        for (int r = 0; r < 16; ++r) rm = fmaxf(rm, st[1][r]);
        rm = fmaxf(rm, __shfl_xor(rm, 32));
        bool defer = __all(rm <= m + THR);
        if (!defer) {
            float mn = fmaxf(m, rm);
            float aq = exp2f((m - mn) * k1);
            m = mn;
            lsum *= aq;
#pragma unroll
            for (int r = 0; r < 16; ++r) {
                int src = (r & 3) + 8 * (r >> 2) + 4 * hi;
                float ar = __shfl(aq, src);
                o[0][r] *= ar;
                o[1][r] *= ar;
            }
        }
        float mk = m * k1;
        float ls = 0.f;
#pragma unroll
        for (int n = 0; n < 2; ++n)
#pragma unroll
            for (int r = 0; r < 16; ++r) {
                float p = exp2f(fmaf(st[n][r], k1, -mk));
                st[n][r] = p;
                ls += p;
            }
        ls += __shfl_xor(ls, 32);
        lsum += ls;

        // P -> bf16 A-frags (cvt_pk + permlane32_swap), PV MFMA
        const char* vbp = (const char*)sVT;
#pragma unroll
        for (int c = 0; c < 4; ++c) {
            const int n = c >> 1, rb = (c & 1) * 8;
            uint A0 = cvtpk(st[n][rb + 0], st[n][rb + 1]);
            uint A1 = cvtpk(st[n][rb + 2], st[n][rb + 3]);
            uint B0 = cvtpk(st[n][rb + 4], st[n][rb + 5]);
            uint B1 = cvtpk(st[n][rb + 6], st[n][rb + 7]);
            plswap(A0, B0);
            plswap(A1, B1);
            union { uint u[4]; bf16x8 v; } pa;
            pa.u[0] = A0; pa.u[1] = A1; pa.u[2] = B0; pa.u[3] = B1;
            int cb = ((c * 2 + hi) & 7) << 4;
            bf16x8 v0 = *(const bf16x8*)(vbp + q32 * 128 + (cb ^ (sw0 << 4)));
            bf16x8 v1 = *(const bf16x8*)(vbp + (32 + q32) * 128 + (cb ^ (sw1 << 4)));
            o[0] = __builtin_amdgcn_mfma_f32_32x32x16_bf16(pa.v, v0, o[0], 0, 0, 0);
            o[1] = __builtin_amdgcn_mfma_f32_32x32x16_bf16(pa.v, v1, o[1], 0, 0, 0);
        }
    }

    // epilogue: O /= l (l gathered per output row), write bf16
#pragma unroll
    for (int r = 0; r < 16; ++r) {
        int srcq = (r & 3) + 8 * (r >> 2) + 4 * hi;
        float li = __shfl(lsum, srcq);
        float inv = 1.f / li;
        int trow = q0 + srcq;
        char* orow = (char*)Ob + ((long)(b * T + trow) * D + h * 64) * 2;
        *(u16*)(orow + q32 * 2) = f2bf(o[0][r] * inv);
        *(u16*)(orow + (32 + q32) * 2) = f2bf(o[1][r] * inv);
    }
}

// ---------------------------------------------------------------------------
extern "C" void kernel_launch(void* const* d_in, const int* in_sizes, int n_in,
                              void* d_out, int out_size, void* d_ws, size_t ws_size,
                              hipStream_t stream) {
    const float* q  = (const float*)d_in[0];
    const float* k  = (const float*)d_in[1];
    const float* v  = (const float*)d_in[2];
    const float* Wq = (const float*)d_in[3];
    const float* bq = (const float*)d_in[4];
    const float* Wk = (const float*)d_in[5];
    const float* bk = (const float*)d_in[6];
    const float* Wv = (const float*)d_in[7];
    const float* bv = (const float*)d_in[8];
    const float* Wo = (const float*)d_in[9];
    const float* bo = (const float*)d_in[10];

    const long MT = 8192L * 1024;
    const long WT = 1024L * 1024;
    u16* ws  = (u16*)d_ws;
    u16* wqb = ws;
    u16* wkb = wqb + WT;
    u16* wvb = wkb + WT;
    u16* wob = wvb + WT;
    u16* xb  = wob + WT;
    u16* qbf = xb + MT;
    u16* kbf = qbf + MT;
    u16* vbf = kbf + MT;
    u16* abf = vbf + MT;

    dim3 blk(256);
    k_f32_to_bf16<<<dim3(512), blk, 0, stream>>>(Wq, wqb, (int)(WT / 8));
    k_f32_to_bf16<<<dim3(512), blk, 0, stream>>>(Wk, wkb, (int)(WT / 8));
    k_f32_to_bf16<<<dim3(512), blk, 0, stream>>>(Wv, wvb, (int)(WT / 8));
    k_f32_to_bf16<<<dim3(512), blk, 0, stream>>>(Wo, wob, (int)(WT / 8));

    dim3 ggrid(512);
    k_f32_to_bf16<<<dim3(4096), blk, 0, stream>>>(q, xb, (int)(MT / 8));
    k_gemm_bt<0><<<ggrid, blk, 0, stream>>>(xb, wqb, bq, nullptr, qbf, 8192, 1024, 1024);
    k_f32_to_bf16<<<dim3(4096), blk, 0, stream>>>(k, xb, (int)(MT / 8));
    k_gemm_bt<0><<<ggrid, blk, 0, stream>>>(xb, wkb, bk, nullptr, kbf, 8192, 1024, 1024);
    k_f32_to_bf16<<<dim3(4096), blk, 0, stream>>>(v, xb, (int)(MT / 8));
    k_gemm_bt<0><<<ggrid, blk, 0, stream>>>(xb, wvb, bv, nullptr, vbf, 8192, 1024, 1024);

    k_attn2<<<dim3(512), dim3(512), 0, stream>>>(qbf, kbf, vbf, abf);

    k_gemm_bt<1><<<ggrid, blk, 0, stream>>>(abf, wob, bo, (float*)d_out, nullptr, 8192, 1024, 1024);
}

// Round 3
// 245.385 us; speedup vs baseline: 1.8288x; 1.1177x over previous
//
#include <hip/hip_runtime.h>
#include <hip/hip_bf16.h>

typedef __bf16 bf16x8 __attribute__((ext_vector_type(8)));
typedef float f32x4 __attribute__((ext_vector_type(4)));
typedef float f32x16 __attribute__((ext_vector_type(16)));
typedef unsigned int uint;
typedef unsigned short u16;

#define DEV static __device__ __forceinline__

DEV u16 f2bf(float x) {
    uint u = __builtin_bit_cast(uint, x);
    u += 0x7FFFu + ((u >> 16) & 1u);
    return (u16)(u >> 16);
}

DEV uint cvtpk(float lo, float hi) {
    uint r;
    asm("v_cvt_pk_bf16_f32 %0, %1, %2" : "=v"(r) : "v"(lo), "v"(hi));
    return r;
}

DEV void plswap(uint& a, uint& b) {
    asm("v_permlane32_swap_b32 %0, %1" : "+v"(a), "+v"(b));
}

DEV float max3f(float a, float b, float c) {
    float d;
    asm("v_max3_f32 %0, %1, %2, %3" : "=v"(d) : "v"(a), "v"(b), "v"(c));
    return d;
}

DEV float fexp2(float x) { return __builtin_amdgcn_exp2f(x); }

DEV void gload16(const void* g, void* l) {
    __builtin_amdgcn_global_load_lds((const __attribute__((address_space(1))) void*)g,
                                     (__attribute__((address_space(3))) void*)l,
                                     16, 0, 0);
}

// 8x8 u16 transpose among lanes (bits 3,4,5 of lane id) -- verified in r1
DEV uint4 xpose8(uint4 vd, int l) {
    uint w0 = vd.x, w1 = vd.y, w2 = vd.z, w3 = vd.w;
    {
        int lam = (l >> 5) & 1;
        uint s0 = lam ? w0 : w2, s1 = lam ? w1 : w3;
        uint t0 = __shfl_xor(s0, 32), t1 = __shfl_xor(s1, 32);
        if (lam) { w0 = t0; w1 = t1; } else { w2 = t0; w3 = t1; }
    }
    {
        int lam = (l >> 4) & 1;
        uint s0 = lam ? w0 : w1, s1 = lam ? w2 : w3;
        uint t0 = __shfl_xor(s0, 16), t1 = __shfl_xor(s1, 16);
        if (lam) { w0 = t0; w2 = t1; } else { w1 = t0; w3 = t1; }
    }
    {
        int lam = (l >> 3) & 1;
        uint sA = lam ? ((w0 & 0xFFFFu) | (w1 << 16)) : ((w0 >> 16) | (w1 & 0xFFFF0000u));
        uint sB = lam ? ((w2 & 0xFFFFu) | (w3 << 16)) : ((w2 >> 16) | (w3 & 0xFFFF0000u));
        uint tA = __shfl_xor(sA, 8), tB = __shfl_xor(sB, 8);
        if (lam) {
            w0 = (w0 & 0xFFFF0000u) | (tA & 0xFFFFu);
            w1 = (w1 & 0xFFFF0000u) | (tA >> 16);
            w2 = (w2 & 0xFFFF0000u) | (tB & 0xFFFFu);
            w3 = (w3 & 0xFFFF0000u) | (tB >> 16);
        } else {
            w0 = (w0 & 0xFFFFu) | (tA << 16);
            w1 = (w1 & 0xFFFFu) | (tA & 0xFFFF0000u);
            w2 = (w2 & 0xFFFFu) | (tB << 16);
            w3 = (w3 & 0xFFFFu) | (tB & 0xFFFF0000u);
        }
    }
    return make_uint4(w0, w1, w2, w3);
}

// ---------------- fp32 -> bf16 conversion ------------------------------------
__global__ __launch_bounds__(256) void k_f32_to_bf16(const float* __restrict__ in,
                                                     u16* __restrict__ out, int n8) {
    int i = blockIdx.x * 256 + threadIdx.x;
    if (i >= n8) return;
    const float4* p = (const float4*)in + (long)i * 2;
    float4 a = p[0], b = p[1];
    u16 r[8];
    r[0] = f2bf(a.x); r[1] = f2bf(a.y); r[2] = f2bf(a.z); r[3] = f2bf(a.w);
    r[4] = f2bf(b.x); r[5] = f2bf(b.y); r[6] = f2bf(b.z); r[7] = f2bf(b.w);
    ((uint4*)out)[i] = *(const uint4*)r;
}

// ---------------- bf16 GEMM, C = A * Bw(seg)^T + bias(seg) -------------------
// seg = bm>>6 selects {Wq,Wk,Wv} stacked weights / biases (merged QKV GEMM);
// for M=8192 seg is always 0.
template <int OUTF32>
__global__ __launch_bounds__(256, 2) void k_gemm_bt(
    const u16* __restrict__ A, const u16* __restrict__ Bw,
    const float* __restrict__ b0, const float* __restrict__ b1,
    const float* __restrict__ b2,
    float* __restrict__ Cf, u16* __restrict__ Cb,
    int M, int N, int K) {
    __shared__ u16 lA[128 * 64];
    __shared__ u16 lB[128 * 64];
    const int tid = threadIdx.x;
    const int l = tid & 63, w = tid >> 6;
    const int lr = l & 15, lk = l >> 4;
    const int wr = w >> 1, wc = w & 1;
    const int nbn = N >> 7;
    // XCD swizzle (grid % 8 == 0): contiguous wg chunk per XCD
    const int cpx = (int)gridDim.x >> 3;
    const int wg = (blockIdx.x & 7) * cpx + (blockIdx.x >> 3);
    const int bm = wg / nbn, bn = wg % nbn;
    const int seg = bm >> 6;
    const u16* Bseg = Bw + ((long)seg << 20);
    const float* bias = seg == 0 ? b0 : (seg == 1 ? b1 : b2);

    long abase[4], bbase[4];
    int ldst[4];
#pragma unroll
    for (int t = 0; t < 4; ++t) {
        int c = t * 256 + tid;
        int p = c * 16;
        int row = p >> 7;
        int inrow = p & 127;
        int src = inrow ^ ((row & 7) << 4);
        ldst[t] = p;
        abase[t] = (long)(bm * 128 + row) * (K * 2) + src;
        bbase[t] = (long)(bn * 128 + row) * (K * 2) + src;
    }
    const int swz = (lr & 7) << 4;
    int aoff[4][2], boff[4][2];
#pragma unroll
    for (int m = 0; m < 4; ++m)
#pragma unroll
        for (int kc = 0; kc < 2; ++kc) {
            aoff[m][kc] = (wr * 64 + m * 16 + lr) * 128 + ((kc * 64 + lk * 16) ^ swz);
            boff[m][kc] = (wc * 64 + m * 16 + lr) * 128 + ((kc * 64 + lk * 16) ^ swz);
        }

    f32x4 acc[4][4] = {};
    const char* gA = (const char*)A;
    const char* gB = (const char*)Bseg;
    const char* lAb = (const char*)lA;
    const char* lBb = (const char*)lB;
    const int nkt = K >> 6;
    for (int kt = 0; kt < nkt; ++kt) {
        __syncthreads();
#pragma unroll
        for (int t = 0; t < 4; ++t)
            gload16(gA + abase[t] + kt * 128, (char*)lA + ldst[t]);
#pragma unroll
        for (int t = 0; t < 4; ++t)
            gload16(gB + bbase[t] + kt * 128, (char*)lB + ldst[t]);
        __syncthreads();
#pragma unroll
        for (int kc = 0; kc < 2; ++kc) {
            bf16x8 av[4], bv[4];
#pragma unroll
            for (int m = 0; m < 4; ++m) av[m] = *(const bf16x8*)(lAb + aoff[m][kc]);
#pragma unroll
            for (int n = 0; n < 4; ++n) bv[n] = *(const bf16x8*)(lBb + boff[n][kc]);
#pragma unroll
            for (int m = 0; m < 4; ++m)
#pragma unroll
                for (int n = 0; n < 4; ++n)
                    acc[m][n] = __builtin_amdgcn_mfma_f32_16x16x32_bf16(av[m], bv[n], acc[m][n], 0, 0, 0);
        }
    }

    const int row0 = bm * 128 + wr * 64;
    const int col0 = bn * 128 + wc * 64;
    float bval[4];
#pragma unroll
    for (int n = 0; n < 4; ++n) bval[n] = bias[col0 + n * 16 + lr];
#pragma unroll
    for (int m = 0; m < 4; ++m)
#pragma unroll
        for (int j = 0; j < 4; ++j) {
            int row = row0 + m * 16 + lk * 4 + j;
#pragma unroll
            for (int n = 0; n < 4; ++n) {
                float v = acc[m][n][j] + bval[n];
                int col = col0 + n * 16 + lr;
                if (OUTF32) Cf[(long)row * N + col] = v;
                else        Cb[(long)row * N + col] = f2bf(v);
            }
        }
}

// ---------------- flash attention v3 ----------------------------------------
// 8 waves x 32 q-rows, KV tile 64, 32x32 MFMA, swapped QK^T, in-register
// softmax, row-sum via MFMA(ones), 1 barrier/tile, dbuf K and V^T.
__global__ __launch_bounds__(512, 4) void k_attn3(
    const u16* __restrict__ Qb, const u16* __restrict__ Kb,
    const u16* __restrict__ Vb, u16* __restrict__ Ob) {
    constexpr int T = 2048, D = 1024;
    __shared__ u16 sK[2][64 * 64];
    __shared__ u16 sVT[2][64 * 64];
    const int tid = threadIdx.x;
    const int l = tid & 63, w = tid >> 6;
    const int hi = l >> 5;
    const int q32 = l & 31;
    const int hi16 = hi * 16;
    const int kswz = (q32 & 7) << 4;
    const int sw0 = (q32 & 7) ^ ((q32 >> 3) & 7);
    const int sw1 = sw0 ^ 4;
    // XCD swizzle: all 8 q-tiles of a head land on one XCD
    const int bid = blockIdx.x;
    const int bh = (bid & 7) * 8 + ((bid >> 3) & 7);
    const int qt = bid >> 6;
    const int b = bh >> 4, h = bh & 15;

    const char* Qg = (const char*)(Qb + (long)b * T * D + h * 64);
    const char* Kg = (const char*)(Kb + (long)b * T * D + h * 64);
    const char* Vg = (const char*)(Vb + (long)b * T * D + h * 64);
    const int q0 = qt * 256 + w * 32;

    bf16x8 qf[4];
#pragma unroll
    for (int c = 0; c < 4; ++c)
        qf[c] = *(const bf16x8*)(Qg + (long)(q0 + q32) * 2048 + c * 32 + hi16);

    const int krow = tid >> 3;
    const int ksrc = ((tid & 7) * 16) ^ ((krow & 7) << 4);
    const int kdst = tid * 16;

    const int vr = l >> 3;
    const int vkv = w * 8 + vr;
    const int vd0 = (l & 7) * 8;
    const int vtd = vd0 + vr;
    const int vtwOff = vtd * 128 + (((w ^ (vtd & 7) ^ ((vtd >> 3) & 7)) & 7) << 4);

    union { u16 s[8]; bf16x8 v; } ones_u;
#pragma unroll
    for (int i = 0; i < 8; ++i) ones_u.s[i] = 0x3F80;
    const bf16x8 onesv = ones_u.v;

    // prologue: K(0) -> sK[0]; V^T(0) -> sVT[0]; start V(1)
    gload16(Kg + (long)krow * 2048 + ksrc, (char*)sK[0] + kdst);
    uint4 vd = *(const uint4*)(Vg + (long)vkv * 2048 + vd0 * 2);
    {
        uint4 t = xpose8(vd, l);
        *(uint4*)((char*)sVT[0] + vtwOff) = t;
    }
    vd = *(const uint4*)(Vg + (long)(64 + vkv) * 2048 + vd0 * 2);
    __syncthreads();

    f32x16 o[2] = {};
    f32x16 lacc = {};
    float m = -1e30f;
    const float k1 = 0.18033688f;          // 0.125 * log2(e)
    const float THR = 44.3616f;            // 8 / k1

    for (int kt = 0; kt < T / 64; ++kt) {
        // stage next K first: in flight across this tile's compute
        if (kt < T / 64 - 1)
            gload16(Kg + (long)((kt + 1) * 64 + krow) * 2048 + ksrc,
                    (char*)sK[(kt + 1) & 1] + kdst);

        // S^T = mfma(K, Q)
        const char* kbp = (const char*)sK[kt & 1];
        f32x16 st[2] = {};
        __builtin_amdgcn_s_setprio(1);
#pragma unroll
        for (int c = 0; c < 4; ++c) {
            bf16x8 kf = *(const bf16x8*)(kbp + q32 * 128 + ((c * 32 + hi16) ^ kswz));
            st[0] = __builtin_amdgcn_mfma_f32_32x32x16_bf16(kf, qf[c], st[0], 0, 0, 0);
        }
#pragma unroll
        for (int c = 0; c < 4; ++c) {
            bf16x8 kf = *(const bf16x8*)(kbp + (32 + q32) * 128 + ((c * 32 + hi16) ^ kswz));
            st[1] = __builtin_amdgcn_mfma_f32_32x32x16_bf16(kf, qf[c], st[1], 0, 0, 0);
        }
        __builtin_amdgcn_s_setprio(0);

        // row max via v_max3 tree (per-lane 32 values)
        float t0 = max3f(st[0][0], st[0][1], st[0][2]);
        float t1 = max3f(st[0][3], st[0][4], st[0][5]);
        float t2 = max3f(st[0][6], st[0][7], st[0][8]);
        float t3 = max3f(st[0][9], st[0][10], st[0][11]);
        float t4 = max3f(st[0][12], st[0][13], st[0][14]);
        float t5 = max3f(st[1][0], st[1][1], st[1][2]);
        float t6 = max3f(st[1][3], st[1][4], st[1][5]);
        float t7 = max3f(st[1][6], st[1][7], st[1][8]);
        float t8 = max3f(st[1][9], st[1][10], st[1][11]);
        float t9 = max3f(st[1][12], st[1][13], st[1][14]);
        float u0 = max3f(t0, t1, t2);
        float u1 = max3f(t3, t4, st[0][15]);
        float u2 = max3f(t5, t6, t7);
        float u3 = max3f(t8, t9, st[1][15]);
        float rm = fmaxf(max3f(u0, u1, u2), u3);

        bool defer = __all(rm <= m + THR);
        if (!defer) {
            float rmw = fmaxf(rm, __shfl_xor(rm, 32));   // sync across lane pair
            float mn = fmaxf(m, rmw);
            float aq = fexp2((m - mn) * k1);
            m = mn;
#pragma unroll
            for (int r = 0; r < 16; ++r) {
                int src = (r & 3) + 8 * (r >> 2) + 4 * hi;
                float ar = __shfl(aq, src);
                o[0][r] *= ar;
                o[1][r] *= ar;
                lacc[r] *= ar;
            }
        }
        float mk = m * k1;
#pragma unroll
        for (int n = 0; n < 2; ++n)
#pragma unroll
            for (int r = 0; r < 16; ++r)
                st[n][r] = fexp2(fmaf(st[n][r], k1, -mk));

        // transpose + write NEXT tile's V^T; start V load 2 ahead
        if (kt < T / 64 - 1) {
            uint4 t = xpose8(vd, l);
            *(uint4*)((char*)sVT[(kt + 1) & 1] + vtwOff) = t;
            if (kt < T / 64 - 2)
                vd = *(const uint4*)(Vg + (long)((kt + 2) * 64 + vkv) * 2048 + vd0 * 2);
        }

        // P -> bf16 A-frags; O += P*V; rowsum via MFMA(ones)
        const char* vbp = (const char*)sVT[kt & 1];
        __builtin_amdgcn_s_setprio(1);
#pragma unroll
        for (int c = 0; c < 4; ++c) {
            const int n = c >> 1, rb = (c & 1) * 8;
            uint A0 = cvtpk(st[n][rb + 0], st[n][rb + 1]);
            uint A1 = cvtpk(st[n][rb + 2], st[n][rb + 3]);
            uint B0 = cvtpk(st[n][rb + 4], st[n][rb + 5]);
            uint B1 = cvtpk(st[n][rb + 6], st[n][rb + 7]);
            plswap(A0, B0);
            plswap(A1, B1);
            union { uint u[4]; bf16x8 v; } pa;
            pa.u[0] = A0; pa.u[1] = A1; pa.u[2] = B0; pa.u[3] = B1;
            int cb = ((c * 2 + hi) & 7) << 4;
            bf16x8 v0 = *(const bf16x8*)(vbp + q32 * 128 + (cb ^ (sw0 << 4)));
            bf16x8 v1 = *(const bf16x8*)(vbp + (32 + q32) * 128 + (cb ^ (sw1 << 4)));
            o[0] = __builtin_amdgcn_mfma_f32_32x32x16_bf16(pa.v, v0, o[0], 0, 0, 0);
            o[1] = __builtin_amdgcn_mfma_f32_32x32x16_bf16(pa.v, v1, o[1], 0, 0, 0);
            lacc  = __builtin_amdgcn_mfma_f32_32x32x16_bf16(pa.v, onesv, lacc, 0, 0, 0);
        }
        __builtin_amdgcn_s_setprio(0);
        __syncthreads();
    }

    // epilogue: O /= rowsum (lacc has identical row layout as o)
#pragma unroll
    for (int r = 0; r < 16; ++r) {
        float inv = 1.f / lacc[r];
        int srcq = (r & 3) + 8 * (r >> 2) + 4 * hi;
        int trow = q0 + srcq;
        char* orow = (char*)Ob + ((long)(b * T + trow) * D + h * 64) * 2;
        *(u16*)(orow + q32 * 2) = f2bf(o[0][r] * inv);
        *(u16*)(orow + (32 + q32) * 2) = f2bf(o[1][r] * inv);
    }
}

// ---------------------------------------------------------------------------
extern "C" void kernel_launch(void* const* d_in, const int* in_sizes, int n_in,
                              void* d_out, int out_size, void* d_ws, size_t ws_size,
                              hipStream_t stream) {
    const float* q  = (const float*)d_in[0];
    const float* k  = (const float*)d_in[1];
    const float* v  = (const float*)d_in[2];
    const float* Wq = (const float*)d_in[3];
    const float* bq = (const float*)d_in[4];
    const float* Wk = (const float*)d_in[5];
    const float* bk = (const float*)d_in[6];
    const float* Wv = (const float*)d_in[7];
    const float* bv = (const float*)d_in[8];
    const float* Wo = (const float*)d_in[9];
    const float* bo = (const float*)d_in[10];

    const long MT = 8192L * 1024;
    const long WT = 1024L * 1024;
    u16* ws   = (u16*)d_ws;
    u16* wqb  = ws;                 // stacked Wq|Wk|Wv (+Wo)
    u16* wob  = ws + 3 * WT;
    u16* xall = ws + 4 * WT;        // stacked q|k|v bf16 activations (3*MT)
    u16* qbf  = xall + 3 * MT;      // stacked Q|K|V outputs (3*MT)
    u16* kbf  = qbf + MT;
    u16* vbf  = kbf + MT;
    u16* abf  = xall;               // attn output reuses xall (dead by then)

    dim3 blk(256);
    k_f32_to_bf16<<<dim3(512), blk, 0, stream>>>(Wq, wqb,          (int)(WT / 8));
    k_f32_to_bf16<<<dim3(512), blk, 0, stream>>>(Wk, wqb + WT,     (int)(WT / 8));
    k_f32_to_bf16<<<dim3(512), blk, 0, stream>>>(Wv, wqb + 2 * WT, (int)(WT / 8));
    k_f32_to_bf16<<<dim3(512), blk, 0, stream>>>(Wo, wob,          (int)(WT / 8));

    k_f32_to_bf16<<<dim3(4096), blk, 0, stream>>>(q, xall,          (int)(MT / 8));
    k_f32_to_bf16<<<dim3(4096), blk, 0, stream>>>(k, xall + MT,     (int)(MT / 8));
    k_f32_to_bf16<<<dim3(4096), blk, 0, stream>>>(v, xall + 2 * MT, (int)(MT / 8));

    // merged QKV projection: M = 3*8192, weights/bias selected by row segment
    k_gemm_bt<0><<<dim3(1536), blk, 0, stream>>>(xall, wqb, bq, bk, bv,
                                                 nullptr, qbf, 24576, 1024, 1024);

    k_attn3<<<dim3(512), dim3(512), 0, stream>>>(qbf, kbf, vbf, abf);

    k_gemm_bt<1><<<dim3(512), blk, 0, stream>>>(abf, wob, bo, bo, bo,
                                                (float*)d_out, nullptr, 8192, 1024, 1024);
}

// Round 4
// 221.016 us; speedup vs baseline: 2.0305x; 1.1103x over previous
//
#include <hip/hip_runtime.h>
#include <hip/hip_bf16.h>

typedef __bf16 bf16x8 __attribute__((ext_vector_type(8)));
typedef float f32x4 __attribute__((ext_vector_type(4)));
typedef float f32x16 __attribute__((ext_vector_type(16)));
typedef unsigned int uint;
typedef unsigned short u16;

#define DEV static __device__ __forceinline__

DEV u16 f2bf(float x) {
    uint u = __builtin_bit_cast(uint, x);
    u += 0x7FFFu + ((u >> 16) & 1u);
    return (u16)(u >> 16);
}

DEV uint cvtpk(float lo, float hi) {
    uint r;
    asm("v_cvt_pk_bf16_f32 %0, %1, %2" : "=v"(r) : "v"(lo), "v"(hi));
    return r;
}

DEV void plswap(uint& a, uint& b) {
    asm("v_permlane32_swap_b32 %0, %1" : "+v"(a), "+v"(b));
}

DEV float max3f(float a, float b, float c) {
    float d;
    asm("v_max3_f32 %0, %1, %2, %3" : "=v"(d) : "v"(a), "v"(b), "v"(c));
    return d;
}

DEV float fexp2(float x) { return __builtin_amdgcn_exp2f(x); }

DEV void gload16(const void* g, void* l) {
    __builtin_amdgcn_global_load_lds((const __attribute__((address_space(1))) void*)g,
                                     (__attribute__((address_space(3))) void*)l,
                                     16, 0, 0);
}

// 8x8 u16 transpose among lanes (bits 3,4,5 of lane id) -- verified r1-r3
DEV uint4 xpose8(uint4 vd, int l) {
    uint w0 = vd.x, w1 = vd.y, w2 = vd.z, w3 = vd.w;
    {
        int lam = (l >> 5) & 1;
        uint s0 = lam ? w0 : w2, s1 = lam ? w1 : w3;
        uint t0 = __shfl_xor(s0, 32), t1 = __shfl_xor(s1, 32);
        if (lam) { w0 = t0; w1 = t1; } else { w2 = t0; w3 = t1; }
    }
    {
        int lam = (l >> 4) & 1;
        uint s0 = lam ? w0 : w1, s1 = lam ? w2 : w3;
        uint t0 = __shfl_xor(s0, 16), t1 = __shfl_xor(s1, 16);
        if (lam) { w0 = t0; w2 = t1; } else { w1 = t0; w3 = t1; }
    }
    {
        int lam = (l >> 3) & 1;
        uint sA = lam ? ((w0 & 0xFFFFu) | (w1 << 16)) : ((w0 >> 16) | (w1 & 0xFFFF0000u));
        uint sB = lam ? ((w2 & 0xFFFFu) | (w3 << 16)) : ((w2 >> 16) | (w3 & 0xFFFF0000u));
        uint tA = __shfl_xor(sA, 8), tB = __shfl_xor(sB, 8);
        if (lam) {
            w0 = (w0 & 0xFFFF0000u) | (tA & 0xFFFFu);
            w1 = (w1 & 0xFFFF0000u) | (tA >> 16);
            w2 = (w2 & 0xFFFF0000u) | (tB & 0xFFFFu);
            w3 = (w3 & 0xFFFF0000u) | (tB >> 16);
        } else {
            w0 = (w0 & 0xFFFFu) | (tA << 16);
            w1 = (w1 & 0xFFFFu) | (tA & 0xFFFF0000u);
            w2 = (w2 & 0xFFFFu) | (tB << 16);
            w3 = (w3 & 0xFFFFu) | (tB & 0xFFFF0000u);
        }
    }
    return make_uint4(w0, w1, w2, w3);
}

// ---------------- all-4-weights fp32 -> bf16, one launch ---------------------
__global__ __launch_bounds__(256) void k_wconv(const float* __restrict__ w0,
                                               const float* __restrict__ w1,
                                               const float* __restrict__ w2,
                                               const float* __restrict__ w3,
                                               u16* __restrict__ out) {
    const int which = blockIdx.x >> 9;
    const float* in = which == 0 ? w0 : (which == 1 ? w1 : (which == 2 ? w2 : w3));
    const long i = (blockIdx.x & 511) * 256 + threadIdx.x;   // 8-elem chunk id
    const float4* p = (const float4*)in + i * 2;
    float4 a = p[0], b = p[1];
    uint4 dv;
    dv.x = cvtpk(a.x, a.y); dv.y = cvtpk(a.z, a.w);
    dv.z = cvtpk(b.x, b.y); dv.w = cvtpk(b.z, b.w);
    ((uint4*)(out + ((long)which << 20)))[i] = dv;
}

// ---------------- fused QKV GEMM: C = cvt_bf16(Aseg_f32) * Bw(seg)^T + b(seg)
// M=24576 (3 segments of 8192 rows -> q,k,v inputs), N=K=1024.
// A reg-staged fp32->bf16 (cvt_pk) into swizzled LDS; B via global_load_lds.
__global__ __launch_bounds__(256, 2) void k_gemm_qkv(
    const float* __restrict__ Aq, const float* __restrict__ Ak,
    const float* __restrict__ Av, const u16* __restrict__ Bw,
    const float* __restrict__ b0, const float* __restrict__ b1,
    const float* __restrict__ b2, u16* __restrict__ Cb) {
    constexpr int N = 1024, K = 1024;
    __shared__ u16 lA[128 * 64];
    __shared__ u16 lB[128 * 64];
    const int tid = threadIdx.x;
    const int l = tid & 63, w = tid >> 6;
    const int lr = l & 15, lk = l >> 4;
    const int wr = w >> 1, wc = w & 1;
    const int nbn = N >> 7;
    const int cpx = (int)gridDim.x >> 3;
    const int wg = (blockIdx.x & 7) * cpx + (blockIdx.x >> 3);
    const int bm = wg / nbn, bn = wg % nbn;
    const int seg = bm >> 6;
    const float* Aseg = seg == 0 ? Aq : (seg == 1 ? Ak : Av);
    const u16* Bseg = Bw + ((long)seg << 20);
    const float* bias = seg == 0 ? b0 : (seg == 1 ? b1 : b2);
    const int bml = bm & 63;

    // A staging: thread covers (row = t*32 + tid>>3, 8 floats at col (tid&7)*8)
    const int arow = tid >> 3;
    const int acol = (tid & 7) * 8;
    int adst[4];
    const float* asrc[4];
#pragma unroll
    for (int t = 0; t < 4; ++t) {
        int row = t * 32 + arow;
        adst[t] = row * 128 + ((acol * 2) ^ ((row & 7) << 4));
        asrc[t] = Aseg + (long)(bml * 128 + row) * K + acol;
    }
    // B staging: gload16 with pre-swizzled source
    long bbase[4];
    int bdst[4];
#pragma unroll
    for (int t = 0; t < 4; ++t) {
        int p = (t * 256 + tid) * 16;
        int row = p >> 7;
        int src = (p & 127) ^ ((row & 7) << 4);
        bdst[t] = p;
        bbase[t] = (long)(bn * 128 + row) * (K * 2) + src;
    }
    const int swz = (lr & 7) << 4;
    int aoff[4][2], boff[4][2];
#pragma unroll
    for (int m = 0; m < 4; ++m)
#pragma unroll
        for (int kc = 0; kc < 2; ++kc) {
            aoff[m][kc] = (wr * 64 + m * 16 + lr) * 128 + ((kc * 64 + lk * 16) ^ swz);
            boff[m][kc] = (wc * 64 + m * 16 + lr) * 128 + ((kc * 64 + lk * 16) ^ swz);
        }

    f32x4 acc[4][4] = {};
    const char* gB = (const char*)Bseg;
    const char* lAb = (const char*)lA;
    const char* lBb = (const char*)lB;
    for (int kt = 0; kt < K / 64; ++kt) {
        __syncthreads();
        // issue B -> LDS first (async), then A fp32 loads, convert, write
#pragma unroll
        for (int t = 0; t < 4; ++t)
            gload16(gB + bbase[t] + kt * 128, (char*)lB + bdst[t]);
        float4 f0[4], f1[4];
#pragma unroll
        for (int t = 0; t < 4; ++t) {
            const float* s = asrc[t] + kt * 64;
            f0[t] = *(const float4*)s;
            f1[t] = *(const float4*)(s + 4);
        }
#pragma unroll
        for (int t = 0; t < 4; ++t) {
            uint4 dv;
            dv.x = cvtpk(f0[t].x, f0[t].y);
            dv.y = cvtpk(f0[t].z, f0[t].w);
            dv.z = cvtpk(f1[t].x, f1[t].y);
            dv.w = cvtpk(f1[t].z, f1[t].w);
            *(uint4*)((char*)lA + adst[t]) = dv;
        }
        __syncthreads();
#pragma unroll
        for (int kc = 0; kc < 2; ++kc) {
            bf16x8 av[4], bv[4];
#pragma unroll
            for (int m = 0; m < 4; ++m) av[m] = *(const bf16x8*)(lAb + aoff[m][kc]);
#pragma unroll
            for (int n = 0; n < 4; ++n) bv[n] = *(const bf16x8*)(lBb + boff[n][kc]);
#pragma unroll
            for (int m = 0; m < 4; ++m)
#pragma unroll
                for (int n = 0; n < 4; ++n)
                    acc[m][n] = __builtin_amdgcn_mfma_f32_16x16x32_bf16(av[m], bv[n], acc[m][n], 0, 0, 0);
        }
    }

    const int row0 = bm * 128 + wr * 64;
    const int col0 = bn * 128 + wc * 64;
    float bval[4];
#pragma unroll
    for (int n = 0; n < 4; ++n) bval[n] = bias[col0 + n * 16 + lr];
#pragma unroll
    for (int m = 0; m < 4; ++m)
#pragma unroll
        for (int j = 0; j < 4; ++j) {
            int row = row0 + m * 16 + lk * 4 + j;
#pragma unroll
            for (int n = 0; n < 4; ++n)
                Cb[(long)row * N + col0 + n * 16 + lr] = f2bf(acc[m][n][j] + bval[n]);
        }
}

// ---------------- bf16 GEMM (Wo projection), fp32 out ------------------------
__global__ __launch_bounds__(256, 2) void k_gemm_bt(
    const u16* __restrict__ A, const u16* __restrict__ Bw,
    const float* __restrict__ bias, float* __restrict__ Cf,
    int M, int N, int K) {
    __shared__ u16 lA[128 * 64];
    __shared__ u16 lB[128 * 64];
    const int tid = threadIdx.x;
    const int l = tid & 63, w = tid >> 6;
    const int lr = l & 15, lk = l >> 4;
    const int wr = w >> 1, wc = w & 1;
    const int nbn = N >> 7;
    const int cpx = (int)gridDim.x >> 3;
    const int wg = (blockIdx.x & 7) * cpx + (blockIdx.x >> 3);
    const int bm = wg / nbn, bn = wg % nbn;

    long abase[4], bbase[4];
    int ldst[4];
#pragma unroll
    for (int t = 0; t < 4; ++t) {
        int c = t * 256 + tid;
        int p = c * 16;
        int row = p >> 7;
        int inrow = p & 127;
        int src = inrow ^ ((row & 7) << 4);
        ldst[t] = p;
        abase[t] = (long)(bm * 128 + row) * (K * 2) + src;
        bbase[t] = (long)(bn * 128 + row) * (K * 2) + src;
    }
    const int swz = (lr & 7) << 4;
    int aoff[4][2], boff[4][2];
#pragma unroll
    for (int m = 0; m < 4; ++m)
#pragma unroll
        for (int kc = 0; kc < 2; ++kc) {
            aoff[m][kc] = (wr * 64 + m * 16 + lr) * 128 + ((kc * 64 + lk * 16) ^ swz);
            boff[m][kc] = (wc * 64 + m * 16 + lr) * 128 + ((kc * 64 + lk * 16) ^ swz);
        }

    f32x4 acc[4][4] = {};
    const char* gA = (const char*)A;
    const char* gB = (const char*)Bw;
    const char* lAb = (const char*)lA;
    const char* lBb = (const char*)lB;
    const int nkt = K >> 6;
    for (int kt = 0; kt < nkt; ++kt) {
        __syncthreads();
#pragma unroll
        for (int t = 0; t < 4; ++t)
            gload16(gA + abase[t] + kt * 128, (char*)lA + ldst[t]);
#pragma unroll
        for (int t = 0; t < 4; ++t)
            gload16(gB + bbase[t] + kt * 128, (char*)lB + ldst[t]);
        __syncthreads();
#pragma unroll
        for (int kc = 0; kc < 2; ++kc) {
            bf16x8 av[4], bv[4];
#pragma unroll
            for (int m = 0; m < 4; ++m) av[m] = *(const bf16x8*)(lAb + aoff[m][kc]);
#pragma unroll
            for (int n = 0; n < 4; ++n) bv[n] = *(const bf16x8*)(lBb + boff[n][kc]);
#pragma unroll
            for (int m = 0; m < 4; ++m)
#pragma unroll
                for (int n = 0; n < 4; ++n)
                    acc[m][n] = __builtin_amdgcn_mfma_f32_16x16x32_bf16(av[m], bv[n], acc[m][n], 0, 0, 0);
        }
    }

    const int row0 = bm * 128 + wr * 64;
    const int col0 = bn * 128 + wc * 64;
    float bval[4];
#pragma unroll
    for (int n = 0; n < 4; ++n) bval[n] = bias[col0 + n * 16 + lr];
#pragma unroll
    for (int m = 0; m < 4; ++m)
#pragma unroll
        for (int j = 0; j < 4; ++j) {
            int row = row0 + m * 16 + lk * 4 + j;
#pragma unroll
            for (int n = 0; n < 4; ++n)
                Cf[(long)row * N + col0 + n * 16 + lr] = acc[m][n][j] + bval[n];
        }
}

// ---------------- flash attention v3 (unchanged from round 3) ----------------
__global__ __launch_bounds__(512, 4) void k_attn3(
    const u16* __restrict__ Qb, const u16* __restrict__ Kb,
    const u16* __restrict__ Vb, u16* __restrict__ Ob) {
    constexpr int T = 2048, D = 1024;
    __shared__ u16 sK[2][64 * 64];
    __shared__ u16 sVT[2][64 * 64];
    const int tid = threadIdx.x;
    const int l = tid & 63, w = tid >> 6;
    const int hi = l >> 5;
    const int q32 = l & 31;
    const int hi16 = hi * 16;
    const int kswz = (q32 & 7) << 4;
    const int sw0 = (q32 & 7) ^ ((q32 >> 3) & 7);
    const int sw1 = sw0 ^ 4;
    const int bid = blockIdx.x;
    const int bh = (bid & 7) * 8 + ((bid >> 3) & 7);
    const int qt = bid >> 6;
    const int b = bh >> 4, h = bh & 15;

    const char* Qg = (const char*)(Qb + (long)b * T * D + h * 64);
    const char* Kg = (const char*)(Kb + (long)b * T * D + h * 64);
    const char* Vg = (const char*)(Vb + (long)b * T * D + h * 64);
    const int q0 = qt * 256 + w * 32;

    bf16x8 qf[4];
#pragma unroll
    for (int c = 0; c < 4; ++c)
        qf[c] = *(const bf16x8*)(Qg + (long)(q0 + q32) * 2048 + c * 32 + hi16);

    const int krow = tid >> 3;
    const int ksrc = ((tid & 7) * 16) ^ ((krow & 7) << 4);
    const int kdst = tid * 16;

    const int vr = l >> 3;
    const int vkv = w * 8 + vr;
    const int vd0 = (l & 7) * 8;
    const int vtd = vd0 + vr;
    const int vtwOff = vtd * 128 + (((w ^ (vtd & 7) ^ ((vtd >> 3) & 7)) & 7) << 4);

    union { u16 s[8]; bf16x8 v; } ones_u;
#pragma unroll
    for (int i = 0; i < 8; ++i) ones_u.s[i] = 0x3F80;
    const bf16x8 onesv = ones_u.v;

    gload16(Kg + (long)krow * 2048 + ksrc, (char*)sK[0] + kdst);
    uint4 vd = *(const uint4*)(Vg + (long)vkv * 2048 + vd0 * 2);
    {
        uint4 t = xpose8(vd, l);
        *(uint4*)((char*)sVT[0] + vtwOff) = t;
    }
    vd = *(const uint4*)(Vg + (long)(64 + vkv) * 2048 + vd0 * 2);
    __syncthreads();

    f32x16 o[2] = {};
    f32x16 lacc = {};
    float m = -1e30f;
    const float k1 = 0.18033688f;
    const float THR = 44.3616f;

    for (int kt = 0; kt < T / 64; ++kt) {
        if (kt < T / 64 - 1)
            gload16(Kg + (long)((kt + 1) * 64 + krow) * 2048 + ksrc,
                    (char*)sK[(kt + 1) & 1] + kdst);

        const char* kbp = (const char*)sK[kt & 1];
        f32x16 st[2] = {};
        __builtin_amdgcn_s_setprio(1);
#pragma unroll
        for (int c = 0; c < 4; ++c) {
            bf16x8 kf = *(const bf16x8*)(kbp + q32 * 128 + ((c * 32 + hi16) ^ kswz));
            st[0] = __builtin_amdgcn_mfma_f32_32x32x16_bf16(kf, qf[c], st[0], 0, 0, 0);
        }
#pragma unroll
        for (int c = 0; c < 4; ++c) {
            bf16x8 kf = *(const bf16x8*)(kbp + (32 + q32) * 128 + ((c * 32 + hi16) ^ kswz));
            st[1] = __builtin_amdgcn_mfma_f32_32x32x16_bf16(kf, qf[c], st[1], 0, 0, 0);
        }
        __builtin_amdgcn_s_setprio(0);

        float t0 = max3f(st[0][0], st[0][1], st[0][2]);
        float t1 = max3f(st[0][3], st[0][4], st[0][5]);
        float t2 = max3f(st[0][6], st[0][7], st[0][8]);
        float t3 = max3f(st[0][9], st[0][10], st[0][11]);
        float t4 = max3f(st[0][12], st[0][13], st[0][14]);
        float t5 = max3f(st[1][0], st[1][1], st[1][2]);
        float t6 = max3f(st[1][3], st[1][4], st[1][5]);
        float t7 = max3f(st[1][6], st[1][7], st[1][8]);
        float t8 = max3f(st[1][9], st[1][10], st[1][11]);
        float t9 = max3f(st[1][12], st[1][13], st[1][14]);
        float u0 = max3f(t0, t1, t2);
        float u1 = max3f(t3, t4, st[0][15]);
        float u2 = max3f(t5, t6, t7);
        float u3 = max3f(t8, t9, st[1][15]);
        float rm = fmaxf(max3f(u0, u1, u2), u3);

        bool defer = __all(rm <= m + THR);
        if (!defer) {
            float rmw = fmaxf(rm, __shfl_xor(rm, 32));
            float mn = fmaxf(m, rmw);
            float aq = fexp2((m - mn) * k1);
            m = mn;
#pragma unroll
            for (int r = 0; r < 16; ++r) {
                int src = (r & 3) + 8 * (r >> 2) + 4 * hi;
                float ar = __shfl(aq, src);
                o[0][r] *= ar;
                o[1][r] *= ar;
                lacc[r] *= ar;
            }
        }
        float mk = m * k1;
#pragma unroll
        for (int n = 0; n < 2; ++n)
#pragma unroll
            for (int r = 0; r < 16; ++r)
                st[n][r] = fexp2(fmaf(st[n][r], k1, -mk));

        if (kt < T / 64 - 1) {
            uint4 t = xpose8(vd, l);
            *(uint4*)((char*)sVT[(kt + 1) & 1] + vtwOff) = t;
            if (kt < T / 64 - 2)
                vd = *(const uint4*)(Vg + (long)((kt + 2) * 64 + vkv) * 2048 + vd0 * 2);
        }

        const char* vbp = (const char*)sVT[kt & 1];
        __builtin_amdgcn_s_setprio(1);
#pragma unroll
        for (int c = 0; c < 4; ++c) {
            const int n = c >> 1, rb = (c & 1) * 8;
            uint A0 = cvtpk(st[n][rb + 0], st[n][rb + 1]);
            uint A1 = cvtpk(st[n][rb + 2], st[n][rb + 3]);
            uint B0 = cvtpk(st[n][rb + 4], st[n][rb + 5]);
            uint B1 = cvtpk(st[n][rb + 6], st[n][rb + 7]);
            plswap(A0, B0);
            plswap(A1, B1);
            union { uint u[4]; bf16x8 v; } pa;
            pa.u[0] = A0; pa.u[1] = A1; pa.u[2] = B0; pa.u[3] = B1;
            int cb = ((c * 2 + hi) & 7) << 4;
            bf16x8 v0 = *(const bf16x8*)(vbp + q32 * 128 + (cb ^ (sw0 << 4)));
            bf16x8 v1 = *(const bf16x8*)(vbp + (32 + q32) * 128 + (cb ^ (sw1 << 4)));
            o[0] = __builtin_amdgcn_mfma_f32_32x32x16_bf16(pa.v, v0, o[0], 0, 0, 0);
            o[1] = __builtin_amdgcn_mfma_f32_32x32x16_bf16(pa.v, v1, o[1], 0, 0, 0);
            lacc  = __builtin_amdgcn_mfma_f32_32x32x16_bf16(pa.v, onesv, lacc, 0, 0, 0);
        }
        __builtin_amdgcn_s_setprio(0);
        __syncthreads();
    }

#pragma unroll
    for (int r = 0; r < 16; ++r) {
        float inv = 1.f / lacc[r];
        int srcq = (r & 3) + 8 * (r >> 2) + 4 * hi;
        int trow = q0 + srcq;
        char* orow = (char*)Ob + ((long)(b * T + trow) * D + h * 64) * 2;
        *(u16*)(orow + q32 * 2) = f2bf(o[0][r] * inv);
        *(u16*)(orow + (32 + q32) * 2) = f2bf(o[1][r] * inv);
    }
}

// ---------------------------------------------------------------------------
extern "C" void kernel_launch(void* const* d_in, const int* in_sizes, int n_in,
                              void* d_out, int out_size, void* d_ws, size_t ws_size,
                              hipStream_t stream) {
    const float* q  = (const float*)d_in[0];
    const float* k  = (const float*)d_in[1];
    const float* v  = (const float*)d_in[2];
    const float* Wq = (const float*)d_in[3];
    const float* bq = (const float*)d_in[4];
    const float* Wk = (const float*)d_in[5];
    const float* bk = (const float*)d_in[6];
    const float* Wv = (const float*)d_in[7];
    const float* bv = (const float*)d_in[8];
    const float* Wo = (const float*)d_in[9];
    const float* bo = (const float*)d_in[10];

    const long MT = 8192L * 1024;
    const long WT = 1024L * 1024;
    u16* ws   = (u16*)d_ws;
    u16* wall = ws;                    // Wq|Wk|Wv|Wo bf16, stacked
    u16* qbf  = wall + 4 * WT;         // Q|K|V bf16 outputs
    u16* kbf  = qbf + MT;
    u16* vbf  = kbf + MT;
    u16* abf  = vbf + MT;              // attention output

    k_wconv<<<dim3(2048), dim3(256), 0, stream>>>(Wq, Wk, Wv, Wo, wall);

    // fused fp32->bf16 + QKV projection (M = 3*8192, seg-selected A/W/bias)
    k_gemm_qkv<<<dim3(1536), dim3(256), 0, stream>>>(q, k, v, wall,
                                                     bq, bk, bv, qbf);

    k_attn3<<<dim3(512), dim3(512), 0, stream>>>(qbf, kbf, vbf, abf);

    k_gemm_bt<<<dim3(512), dim3(256), 0, stream>>>(abf, wall + 3 * WT, bo,
                                                   (float*)d_out, 8192, 1024, 1024);
}

// Round 6
// 191.086 us; speedup vs baseline: 2.3485x; 1.1566x over previous
//
#include <hip/hip_runtime.h>
#include <hip/hip_bf16.h>

typedef __bf16 bf16x8 __attribute__((ext_vector_type(8)));
typedef float f32x4 __attribute__((ext_vector_type(4)));
typedef float f32x16 __attribute__((ext_vector_type(16)));
typedef unsigned int uint;
typedef unsigned short u16;

#define DEV static __device__ __forceinline__

DEV u16 f2bf(float x) {
    uint u = __builtin_bit_cast(uint, x);
    u += 0x7FFFu + ((u >> 16) & 1u);
    return (u16)(u >> 16);
}

DEV uint cvtpk(float lo, float hi) {
    uint r;
    asm("v_cvt_pk_bf16_f32 %0, %1, %2" : "=v"(r) : "v"(lo), "v"(hi));
    return r;
}

DEV void plswap(uint& a, uint& b) {
    asm("v_permlane32_swap_b32 %0, %1" : "+v"(a), "+v"(b));
}

DEV float max3f(float a, float b, float c) {
    float d;
    asm("v_max3_f32 %0, %1, %2, %3" : "=v"(d) : "v"(a), "v"(b), "v"(c));
    return d;
}

DEV float fexp2(float x) { return __builtin_amdgcn_exp2f(x); }

DEV void gload16(const void* g, void* l) {
    __builtin_amdgcn_global_load_lds((const __attribute__((address_space(1))) void*)g,
                                     (__attribute__((address_space(3))) void*)l,
                                     16, 0, 0);
}

// ---------------- all-4-weights fp32 -> bf16, one launch ---------------------
__global__ __launch_bounds__(256) void k_wconv(const float* __restrict__ w0,
                                               const float* __restrict__ w1,
                                               const float* __restrict__ w2,
                                               const float* __restrict__ w3,
                                               u16* __restrict__ out) {
    const int which = blockIdx.x >> 9;
    const float* in = which == 0 ? w0 : (which == 1 ? w1 : (which == 2 ? w2 : w3));
    const long i = (blockIdx.x & 511) * 256 + threadIdx.x;
    const float4* p = (const float4*)in + i * 2;
    float4 a = p[0], b = p[1];
    uint4 dv;
    dv.x = cvtpk(a.x, a.y); dv.y = cvtpk(a.z, a.w);
    dv.z = cvtpk(b.x, b.y); dv.w = cvtpk(b.z, b.w);
    ((uint4*)(out + ((long)which << 20)))[i] = dv;
}

// ---------------- fused QKV GEMM (fp32 A -> bf16 in-kernel) ------------------
// seg 0/1 (Q,K): row-major [8192][1024] into Cb.
// seg 2 (V): transposed write VT[bh][dh][t] (bh = b*16+h, dh<64, t<2048) --
// attention consumes V^T only, so no row-major V is ever materialized.
__global__ __launch_bounds__(256, 2) void k_gemm_qkv(
    const float* __restrict__ Aq, const float* __restrict__ Ak,
    const float* __restrict__ Av, const u16* __restrict__ Bw,
    const float* __restrict__ b0, const float* __restrict__ b1,
    const float* __restrict__ b2, u16* __restrict__ Cb,
    u16* __restrict__ VT) {
    constexpr int N = 1024, K = 1024;
    __shared__ u16 lA[128 * 64];
    __shared__ u16 lB[128 * 64];
    const int tid = threadIdx.x;
    const int l = tid & 63, w = tid >> 6;
    const int lr = l & 15, lk = l >> 4;
    const int wr = w >> 1, wc = w & 1;
    const int nbn = N >> 7;
    const int cpx = (int)gridDim.x >> 3;
    const int wg = (blockIdx.x & 7) * cpx + (blockIdx.x >> 3);
    const int bm = wg / nbn, bn = wg % nbn;
    const int seg = bm >> 6;
    const float* Aseg = seg == 0 ? Aq : (seg == 1 ? Ak : Av);
    const u16* Bseg = Bw + ((long)seg << 20);
    const float* bias = seg == 0 ? b0 : (seg == 1 ? b1 : b2);
    const int bml = bm & 63;

    const int arow = tid >> 3;
    const int acol = (tid & 7) * 8;
    int adst[4];
    const float* asrc[4];
#pragma unroll
    for (int t = 0; t < 4; ++t) {
        int row = t * 32 + arow;
        adst[t] = row * 128 + ((acol * 2) ^ ((row & 7) << 4));
        asrc[t] = Aseg + (long)(bml * 128 + row) * K + acol;
    }
    long bbase[4];
    int bdst[4];
#pragma unroll
    for (int t = 0; t < 4; ++t) {
        int p = (t * 256 + tid) * 16;
        int row = p >> 7;
        int src = (p & 127) ^ ((row & 7) << 4);
        bdst[t] = p;
        bbase[t] = (long)(bn * 128 + row) * (K * 2) + src;
    }
    const int swz = (lr & 7) << 4;
    int aoff[4][2], boff[4][2];
#pragma unroll
    for (int m = 0; m < 4; ++m)
#pragma unroll
        for (int kc = 0; kc < 2; ++kc) {
            aoff[m][kc] = (wr * 64 + m * 16 + lr) * 128 + ((kc * 64 + lk * 16) ^ swz);
            boff[m][kc] = (wc * 64 + m * 16 + lr) * 128 + ((kc * 64 + lk * 16) ^ swz);
        }

    f32x4 acc[4][4] = {};
    const char* gB = (const char*)Bseg;
    const char* lAb = (const char*)lA;
    const char* lBb = (const char*)lB;
    for (int kt = 0; kt < K / 64; ++kt) {
        __syncthreads();
#pragma unroll
        for (int t = 0; t < 4; ++t)
            gload16(gB + bbase[t] + kt * 128, (char*)lB + bdst[t]);
        float4 f0[4], f1[4];
#pragma unroll
        for (int t = 0; t < 4; ++t) {
            const float* s = asrc[t] + kt * 64;
            f0[t] = *(const float4*)s;
            f1[t] = *(const float4*)(s + 4);
        }
#pragma unroll
        for (int t = 0; t < 4; ++t) {
            uint4 dv;
            dv.x = cvtpk(f0[t].x, f0[t].y);
            dv.y = cvtpk(f0[t].z, f0[t].w);
            dv.z = cvtpk(f1[t].x, f1[t].y);
            dv.w = cvtpk(f1[t].z, f1[t].w);
            *(uint4*)((char*)lA + adst[t]) = dv;
        }
        __syncthreads();
#pragma unroll
        for (int kc = 0; kc < 2; ++kc) {
            bf16x8 av[4], bv[4];
#pragma unroll
            for (int m = 0; m < 4; ++m) av[m] = *(const bf16x8*)(lAb + aoff[m][kc]);
#pragma unroll
            for (int n = 0; n < 4; ++n) bv[n] = *(const bf16x8*)(lBb + boff[n][kc]);
#pragma unroll
            for (int m = 0; m < 4; ++m)
#pragma unroll
                for (int n = 0; n < 4; ++n)
                    acc[m][n] = __builtin_amdgcn_mfma_f32_16x16x32_bf16(av[m], bv[n], acc[m][n], 0, 0, 0);
        }
    }

    const int col0 = bn * 128 + wc * 64;
    float bval[4];
#pragma unroll
    for (int n = 0; n < 4; ++n) bval[n] = bias[col0 + n * 16 + lr];

    if (seg < 2) {
        const int row0 = bm * 128 + wr * 64;
#pragma unroll
        for (int m = 0; m < 4; ++m)
#pragma unroll
            for (int j = 0; j < 4; ++j) {
                int row = row0 + m * 16 + lk * 4 + j;
#pragma unroll
                for (int n = 0; n < 4; ++n)
                    Cb[(long)row * N + col0 + n * 16 + lr] = f2bf(acc[m][n][j] + bval[n]);
            }
    } else {
        // V^T write: VT[(b*16+h)*64 + dh][t]
        const int r0 = bml * 128 + wr * 64;
#pragma unroll
        for (int m = 0; m < 4; ++m)
#pragma unroll
            for (int j = 0; j < 4; ++j) {
                int r8 = r0 + m * 16 + lk * 4 + j;       // token idx in 8192
                int bb = r8 >> 11, t = r8 & 2047;
#pragma unroll
                for (int n = 0; n < 4; ++n) {
                    int col = col0 + n * 16 + lr;        // channel
                    int hh = col >> 6, dh = col & 63;
                    VT[(((long)(bb * 16 + hh) * 64 + dh) << 11) + t] =
                        f2bf(acc[m][n][j] + bval[n]);
                }
            }
    }
}

// ---------------- bf16 GEMM (Wo projection), fp32 out ------------------------
__global__ __launch_bounds__(256, 2) void k_gemm_bt(
    const u16* __restrict__ A, const u16* __restrict__ Bw,
    const float* __restrict__ bias, float* __restrict__ Cf,
    int M, int N, int K) {
    __shared__ u16 lA[128 * 64];
    __shared__ u16 lB[128 * 64];
    const int tid = threadIdx.x;
    const int l = tid & 63, w = tid >> 6;
    const int lr = l & 15, lk = l >> 4;
    const int wr = w >> 1, wc = w & 1;
    const int nbn = N >> 7;
    const int cpx = (int)gridDim.x >> 3;
    const int wg = (blockIdx.x & 7) * cpx + (blockIdx.x >> 3);
    const int bm = wg / nbn, bn = wg % nbn;

    long abase[4], bbase[4];
    int ldst[4];
#pragma unroll
    for (int t = 0; t < 4; ++t) {
        int c = t * 256 + tid;
        int p = c * 16;
        int row = p >> 7;
        int inrow = p & 127;
        int src = inrow ^ ((row & 7) << 4);
        ldst[t] = p;
        abase[t] = (long)(bm * 128 + row) * (K * 2) + src;
        bbase[t] = (long)(bn * 128 + row) * (K * 2) + src;
    }
    const int swz = (lr & 7) << 4;
    int aoff[4][2], boff[4][2];
#pragma unroll
    for (int m = 0; m < 4; ++m)
#pragma unroll
        for (int kc = 0; kc < 2; ++kc) {
            aoff[m][kc] = (wr * 64 + m * 16 + lr) * 128 + ((kc * 64 + lk * 16) ^ swz);
            boff[m][kc] = (wc * 64 + m * 16 + lr) * 128 + ((kc * 64 + lk * 16) ^ swz);
        }

    f32x4 acc[4][4] = {};
    const char* gA = (const char*)A;
    const char* gB = (const char*)Bw;
    const char* lAb = (const char*)lA;
    const char* lBb = (const char*)lB;
    const int nkt = K >> 6;
    for (int kt = 0; kt < nkt; ++kt) {
        __syncthreads();
#pragma unroll
        for (int t = 0; t < 4; ++t)
            gload16(gA + abase[t] + kt * 128, (char*)lA + ldst[t]);
#pragma unroll
        for (int t = 0; t < 4; ++t)
            gload16(gB + bbase[t] + kt * 128, (char*)lB + ldst[t]);
        __syncthreads();
#pragma unroll
        for (int kc = 0; kc < 2; ++kc) {
            bf16x8 av[4], bv[4];
#pragma unroll
            for (int m = 0; m < 4; ++m) av[m] = *(const bf16x8*)(lAb + aoff[m][kc]);
#pragma unroll
            for (int n = 0; n < 4; ++n) bv[n] = *(const bf16x8*)(lBb + boff[n][kc]);
#pragma unroll
            for (int m = 0; m < 4; ++m)
#pragma unroll
                for (int n = 0; n < 4; ++n)
                    acc[m][n] = __builtin_amdgcn_mfma_f32_16x16x32_bf16(av[m], bv[n], acc[m][n], 0, 0, 0);
        }
    }

    const int row0 = bm * 128 + wr * 64;
    const int col0 = bn * 128 + wc * 64;
    float bval[4];
#pragma unroll
    for (int n = 0; n < 4; ++n) bval[n] = bias[col0 + n * 16 + lr];
#pragma unroll
    for (int m = 0; m < 4; ++m)
#pragma unroll
        for (int j = 0; j < 4; ++j) {
            int row = row0 + m * 16 + lk * 4 + j;
#pragma unroll
            for (int n = 0; n < 4; ++n)
                Cf[(long)row * N + col0 + n * 16 + lr] = acc[m][n][j] + bval[n];
        }
}

// ---------------- flash attention v5: V^T pre-transposed in global -----------
// Both K and V^T staged via global_load_lds (pre-swizzled src, XOR'd reads).
// No in-kernel transpose; K-read and V-read use the identical verified path.
__global__ __launch_bounds__(512, 4) void k_attn5(
    const u16* __restrict__ Qb, const u16* __restrict__ Kb,
    const u16* __restrict__ VTb, u16* __restrict__ Ob) {
    constexpr int T = 2048, D = 1024;
    constexpr int NT = T / 64;
    __shared__ u16 sK[2][4096];     // [buf][kv][d-slice], XOR-swizzled rows
    __shared__ u16 sV[2][4096];     // [buf][d][kv-slice], XOR-swizzled rows
    const int tid = threadIdx.x;
    const int l = tid & 63, w = tid >> 6;
    const int hi = l >> 5;
    const int q32 = l & 31;
    const int hi16 = hi * 16;
    const int kswz = (q32 & 7) << 4;
    const int bid = blockIdx.x;
    const int bh = (bid & 7) * 8 + ((bid >> 3) & 7);
    const int qt = bid >> 6;
    const int b = bh >> 4, h = bh & 15;

    const char* Qg = (const char*)(Qb + (long)b * T * D + h * 64);
    const char* Kg = (const char*)(Kb + (long)b * T * D + h * 64);
    const char* VTg = (const char*)(VTb + (long)bh * 64 * 2048);
    const int q0 = qt * 256 + w * 32;

    bf16x8 qf[4];
#pragma unroll
    for (int c = 0; c < 4; ++c)
        qf[c] = *(const bf16x8*)(Qg + (long)(q0 + q32) * 2048 + c * 32 + hi16);

    // staging: 512 threads x 16B = one 8KB tile each for K and VT
    const int srow = tid >> 3;
    const int ssrc = ((tid & 7) * 16) ^ ((srow & 7) << 4);
    const int sdst = tid * 16;
    const long kbase = (long)srow * 2048 + ssrc;   // K row stride = D*2 bytes
    const long vbase = (long)srow * 4096 + ssrc;   // VT row stride = T*2 bytes

    union { u16 s[8]; bf16x8 v; } ones_u;
#pragma unroll
    for (int i = 0; i < 8; ++i) ones_u.s[i] = 0x3F80;
    const bf16x8 onesv = ones_u.v;

#define STAGE(kt_, buf_) do {                                                  \
        gload16(Kg + (long)(kt_) * 64 * 2048 + kbase, (char*)sK[buf_] + sdst); \
        gload16(VTg + (kt_) * 128 + vbase, (char*)sV[buf_] + sdst);            \
    } while (0)

    STAGE(0, 0);
    __syncthreads();

    f32x16 o[2] = {};
    f32x16 lacc = {};
    float m = -1e30f;
    const float k1 = 0.18033688f;          // 0.125 * log2(e)
    const float THR = 44.3616f;            // 8 / k1

    for (int kt = 0; kt < NT; ++kt) {
        if (kt + 1 < NT) STAGE(kt + 1, (kt + 1) & 1);

        // S^T = mfma(K, Q)
        const char* kbp = (const char*)sK[kt & 1];
        f32x16 st[2] = {};
        __builtin_amdgcn_s_setprio(1);
#pragma unroll
        for (int c = 0; c < 4; ++c) {
            bf16x8 kf = *(const bf16x8*)(kbp + q32 * 128 + ((c * 32 + hi16) ^ kswz));
            st[0] = __builtin_amdgcn_mfma_f32_32x32x16_bf16(kf, qf[c], st[0], 0, 0, 0);
        }
#pragma unroll
        for (int c = 0; c < 4; ++c) {
            bf16x8 kf = *(const bf16x8*)(kbp + (32 + q32) * 128 + ((c * 32 + hi16) ^ kswz));
            st[1] = __builtin_amdgcn_mfma_f32_32x32x16_bf16(kf, qf[c], st[1], 0, 0, 0);
        }
        __builtin_amdgcn_s_setprio(0);

        // row max via v_max3 tree
        float t0 = max3f(st[0][0], st[0][1], st[0][2]);
        float t1 = max3f(st[0][3], st[0][4], st[0][5]);
        float t2 = max3f(st[0][6], st[0][7], st[0][8]);
        float t3 = max3f(st[0][9], st[0][10], st[0][11]);
        float t4 = max3f(st[0][12], st[0][13], st[0][14]);
        float t5 = max3f(st[1][0], st[1][1], st[1][2]);
        float t6 = max3f(st[1][3], st[1][4], st[1][5]);
        float t7 = max3f(st[1][6], st[1][7], st[1][8]);
        float t8 = max3f(st[1][9], st[1][10], st[1][11]);
        float t9 = max3f(st[1][12], st[1][13], st[1][14]);
        float u0 = max3f(t0, t1, t2);
        float u1 = max3f(t3, t4, st[0][15]);
        float u2 = max3f(t5, t6, t7);
        float u3 = max3f(t8, t9, st[1][15]);
        float rm = fmaxf(max3f(u0, u1, u2), u3);

        bool defer = __all(rm <= m + THR);
        if (!defer) {
            float rmw = fmaxf(rm, __shfl_xor(rm, 32));
            float mn = fmaxf(m, rmw);
            float aq = fexp2((m - mn) * k1);
            m = mn;
#pragma unroll
            for (int r = 0; r < 16; ++r) {
                int src = (r & 3) + 8 * (r >> 2) + 4 * hi;
                float ar = __shfl(aq, src);
                o[0][r] *= ar;
                o[1][r] *= ar;
                lacc[r] *= ar;
            }
        }
        float mk = m * k1;
#pragma unroll
        for (int n = 0; n < 2; ++n)
#pragma unroll
            for (int r = 0; r < 16; ++r)
                st[n][r] = fexp2(fmaf(st[n][r], k1, -mk));

        // P -> bf16 A-frags; O += P*V; rowsum via MFMA(ones)
        const char* vbp = (const char*)sV[kt & 1];
        __builtin_amdgcn_s_setprio(1);
#pragma unroll
        for (int c = 0; c < 4; ++c) {
            const int n = c >> 1, rb = (c & 1) * 8;
            uint A0 = cvtpk(st[n][rb + 0], st[n][rb + 1]);
            uint A1 = cvtpk(st[n][rb + 2], st[n][rb + 3]);
            uint B0 = cvtpk(st[n][rb + 4], st[n][rb + 5]);
            uint B1 = cvtpk(st[n][rb + 6], st[n][rb + 7]);
            plswap(A0, B0);
            plswap(A1, B1);
            union { uint u[4]; bf16x8 v; } pa;
            pa.u[0] = A0; pa.u[1] = A1; pa.u[2] = B0; pa.u[3] = B1;
            int cb = c * 32 + hi16;
            bf16x8 v0 = *(const bf16x8*)(vbp + q32 * 128 + (cb ^ kswz));
            bf16x8 v1 = *(const bf16x8*)(vbp + (32 + q32) * 128 + (cb ^ kswz));
            o[0] = __builtin_amdgcn_mfma_f32_32x32x16_bf16(pa.v, v0, o[0], 0, 0, 0);
            o[1] = __builtin_amdgcn_mfma_f32_32x32x16_bf16(pa.v, v1, o[1], 0, 0, 0);
            lacc  = __builtin_amdgcn_mfma_f32_32x32x16_bf16(pa.v, onesv, lacc, 0, 0, 0);
        }
        __builtin_amdgcn_s_setprio(0);
        __syncthreads();
    }
#undef STAGE

    // epilogue: O /= rowsum
#pragma unroll
    for (int r = 0; r < 16; ++r) {
        float inv = 1.f / lacc[r];
        int srcq = (r & 3) + 8 * (r >> 2) + 4 * hi;
        int trow = q0 + srcq;
        char* orow = (char*)Ob + ((long)(b * T + trow) * D + h * 64) * 2;
        *(u16*)(orow + q32 * 2) = f2bf(o[0][r] * inv);
        *(u16*)(orow + (32 + q32) * 2) = f2bf(o[1][r] * inv);
    }
}

// ---------------------------------------------------------------------------
extern "C" void kernel_launch(void* const* d_in, const int* in_sizes, int n_in,
                              void* d_out, int out_size, void* d_ws, size_t ws_size,
                              hipStream_t stream) {
    const float* q  = (const float*)d_in[0];
    const float* k  = (const float*)d_in[1];
    const float* v  = (const float*)d_in[2];
    const float* Wq = (const float*)d_in[3];
    const float* bq = (const float*)d_in[4];
    const float* Wk = (const float*)d_in[5];
    const float* bk = (const float*)d_in[6];
    const float* Wv = (const float*)d_in[7];
    const float* bv = (const float*)d_in[8];
    const float* Wo = (const float*)d_in[9];
    const float* bo = (const float*)d_in[10];

    const long MT = 8192L * 1024;
    const long WT = 1024L * 1024;
    u16* ws   = (u16*)d_ws;
    u16* wall = ws;                    // Wq|Wk|Wv|Wo bf16, stacked
    u16* qbf  = wall + 4 * WT;         // Q|K row-major outputs
    u16* kbf  = qbf + MT;
    u16* vtb  = kbf + MT;              // V^T [bh][dh][t]
    u16* abf  = vtb + MT;              // attention output

    k_wconv<<<dim3(2048), dim3(256), 0, stream>>>(Wq, Wk, Wv, Wo, wall);

    k_gemm_qkv<<<dim3(1536), dim3(256), 0, stream>>>(q, k, v, wall,
                                                     bq, bk, bv, qbf, vtb);

    k_attn5<<<dim3(512), dim3(512), 0, stream>>>(qbf, kbf, vtb, abf);

    k_gemm_bt<<<dim3(512), dim3(256), 0, stream>>>(abf, wall + 3 * WT, bo,
                                                   (float*)d_out, 8192, 1024, 1024);
}

// Round 7
// 185.840 us; speedup vs baseline: 2.4148x; 1.0282x over previous
//
#include <hip/hip_runtime.h>
#include <hip/hip_bf16.h>

typedef __bf16 bf16x8 __attribute__((ext_vector_type(8)));
typedef float f32x4 __attribute__((ext_vector_type(4)));
typedef float f32x16 __attribute__((ext_vector_type(16)));
typedef unsigned int uint;
typedef unsigned short u16;

#define DEV static __device__ __forceinline__

DEV u16 f2bf(float x) {
    uint u = __builtin_bit_cast(uint, x);
    u += 0x7FFFu + ((u >> 16) & 1u);
    return (u16)(u >> 16);
}

DEV uint cvtpk(float lo, float hi) {
    uint r;
    asm("v_cvt_pk_bf16_f32 %0, %1, %2" : "=v"(r) : "v"(lo), "v"(hi));
    return r;
}

DEV void plswap(uint& a, uint& b) {
    asm("v_permlane32_swap_b32 %0, %1" : "+v"(a), "+v"(b));
}

DEV float max3f(float a, float b, float c) {
    float d;
    asm("v_max3_f32 %0, %1, %2, %3" : "=v"(d) : "v"(a), "v"(b), "v"(c));
    return d;
}

DEV float fexp2(float x) { return __builtin_amdgcn_exp2f(x); }

DEV void gload16(const void* g, void* l) {
    __builtin_amdgcn_global_load_lds((const __attribute__((address_space(1))) void*)g,
                                     (__attribute__((address_space(3))) void*)l,
                                     16, 0, 0);
}

// ---------------- all-4-weights fp32 -> bf16, one launch ---------------------
__global__ __launch_bounds__(256) void k_wconv(const float* __restrict__ w0,
                                               const float* __restrict__ w1,
                                               const float* __restrict__ w2,
                                               const float* __restrict__ w3,
                                               u16* __restrict__ out) {
    const int which = blockIdx.x >> 9;
    const float* in = which == 0 ? w0 : (which == 1 ? w1 : (which == 2 ? w2 : w3));
    const long i = (blockIdx.x & 511) * 256 + threadIdx.x;
    const float4* p = (const float4*)in + i * 2;
    float4 a = p[0], b = p[1];
    uint4 dv;
    dv.x = cvtpk(a.x, a.y); dv.y = cvtpk(a.z, a.w);
    dv.z = cvtpk(b.x, b.y); dv.w = cvtpk(b.z, b.w);
    ((uint4*)(out + ((long)which << 20)))[i] = dv;
}

// ---------------- fused QKV GEMM (fp32 A -> bf16 in-kernel) ------------------
// seg 0/1 (Q,K): row-major [8192][1024] into Cb.
// seg 2 (V): V^T write via LDS-transpose epilogue -> VT[bh][dh][t], stores in
// 256B contiguous segments (16 lanes x 16B per channel row).
__global__ __launch_bounds__(256, 2) void k_gemm_qkv(
    const float* __restrict__ Aq, const float* __restrict__ Ak,
    const float* __restrict__ Av, const u16* __restrict__ Bw,
    const float* __restrict__ b0, const float* __restrict__ b1,
    const float* __restrict__ b2, u16* __restrict__ Cb,
    u16* __restrict__ VT) {
    constexpr int N = 1024, K = 1024;
    __shared__ u16 lS[16384];           // lA = lS[0:8192], lB = lS[8192:16384]
    u16* lA = lS;
    u16* lB = lS + 8192;
    const int tid = threadIdx.x;
    const int l = tid & 63, w = tid >> 6;
    const int lr = l & 15, lk = l >> 4;
    const int wr = w >> 1, wc = w & 1;
    const int nbn = N >> 7;
    const int cpx = (int)gridDim.x >> 3;
    const int wg = (blockIdx.x & 7) * cpx + (blockIdx.x >> 3);
    const int bm = wg / nbn, bn = wg % nbn;
    const int seg = bm >> 6;
    const float* Aseg = seg == 0 ? Aq : (seg == 1 ? Ak : Av);
    const u16* Bseg = Bw + ((long)seg << 20);
    const float* bias = seg == 0 ? b0 : (seg == 1 ? b1 : b2);
    const int bml = bm & 63;

    const int arow = tid >> 3;
    const int acol = (tid & 7) * 8;
    int adst[4];
    const float* asrc[4];
#pragma unroll
    for (int t = 0; t < 4; ++t) {
        int row = t * 32 + arow;
        adst[t] = row * 128 + ((acol * 2) ^ ((row & 7) << 4));
        asrc[t] = Aseg + (long)(bml * 128 + row) * K + acol;
    }
    long bbase[4];
    int bdst[4];
#pragma unroll
    for (int t = 0; t < 4; ++t) {
        int p = (t * 256 + tid) * 16;
        int row = p >> 7;
        int src = (p & 127) ^ ((row & 7) << 4);
        bdst[t] = p;
        bbase[t] = (long)(bn * 128 + row) * (K * 2) + src;
    }
    const int swz = (lr & 7) << 4;
    int aoff[4][2], boff[4][2];
#pragma unroll
    for (int m = 0; m < 4; ++m)
#pragma unroll
        for (int kc = 0; kc < 2; ++kc) {
            aoff[m][kc] = (wr * 64 + m * 16 + lr) * 128 + ((kc * 64 + lk * 16) ^ swz);
            boff[m][kc] = (wc * 64 + m * 16 + lr) * 128 + ((kc * 64 + lk * 16) ^ swz);
        }

    f32x4 acc[4][4] = {};
    const char* gB = (const char*)Bseg;
    const char* lAb = (const char*)lA;
    const char* lBb = (const char*)lB;
    for (int kt = 0; kt < K / 64; ++kt) {
        __syncthreads();
#pragma unroll
        for (int t = 0; t < 4; ++t)
            gload16(gB + bbase[t] + kt * 128, (char*)lB + bdst[t]);
        float4 f0[4], f1[4];
#pragma unroll
        for (int t = 0; t < 4; ++t) {
            const float* s = asrc[t] + kt * 64;
            f0[t] = *(const float4*)s;
            f1[t] = *(const float4*)(s + 4);
        }
#pragma unroll
        for (int t = 0; t < 4; ++t) {
            uint4 dv;
            dv.x = cvtpk(f0[t].x, f0[t].y);
            dv.y = cvtpk(f0[t].z, f0[t].w);
            dv.z = cvtpk(f1[t].x, f1[t].y);
            dv.w = cvtpk(f1[t].z, f1[t].w);
            *(uint4*)((char*)lA + adst[t]) = dv;
        }
        __syncthreads();
#pragma unroll
        for (int kc = 0; kc < 2; ++kc) {
            bf16x8 av[4], bv[4];
#pragma unroll
            for (int m = 0; m < 4; ++m) av[m] = *(const bf16x8*)(lAb + aoff[m][kc]);
#pragma unroll
            for (int n = 0; n < 4; ++n) bv[n] = *(const bf16x8*)(lBb + boff[n][kc]);
#pragma unroll
            for (int m = 0; m < 4; ++m)
#pragma unroll
                for (int n = 0; n < 4; ++n)
                    acc[m][n] = __builtin_amdgcn_mfma_f32_16x16x32_bf16(av[m], bv[n], acc[m][n], 0, 0, 0);
        }
    }

    const int col0 = bn * 128 + wc * 64;
    float bval[4];
#pragma unroll
    for (int n = 0; n < 4; ++n) bval[n] = bias[col0 + n * 16 + lr];

    if (seg < 2) {
        const int row0 = bm * 128 + wr * 64;
#pragma unroll
        for (int m = 0; m < 4; ++m)
#pragma unroll
            for (int j = 0; j < 4; ++j) {
                int row = row0 + m * 16 + lk * 4 + j;
#pragma unroll
                for (int n = 0; n < 4; ++n)
                    Cb[(long)row * N + col0 + n * 16 + lr] = f2bf(acc[m][n][j] + bval[n]);
            }
    } else {
        // LDS-transpose epilogue: tile [token 128][channel 128] -> lS[channel][token]
        __syncthreads();   // all waves done reading lA/lB
#pragma unroll
        for (int m = 0; m < 4; ++m)
#pragma unroll
            for (int j = 0; j < 4; ++j) {
                int row = wr * 64 + m * 16 + lk * 4 + j;        // local token
#pragma unroll
                for (int n = 0; n < 4; ++n) {
                    int col = wc * 64 + n * 16 + lr;            // local channel
                    *(u16*)((char*)lS + col * 256 + ((row * 2) ^ ((col & 7) << 4))) =
                        f2bf(acc[m][n][j] + bval[n]);
                }
            }
        __syncthreads();
        const int bb = bml >> 4;               // batch
        const int t0 = (bml & 15) * 128;       // token base within batch
        const int c = tid >> 4;                // local channel (pass 0)
        const int chunk = tid & 15;            // 16B chunk within 256B row
#pragma unroll
        for (int pass = 0; pass < 8; ++pass) {
            int cc = pass * 16 + c;
            uint4 val = *(const uint4*)((const char*)lS + cc * 256 +
                                        ((chunk * 16) ^ ((cc & 7) << 4)));
            int gcol = bn * 128 + cc;
            int hh = gcol >> 6, dh = gcol & 63;
            *(uint4*)((char*)VT +
                      ((((long)(bb * 16 + hh) * 64 + dh) << 11) + t0 + chunk * 8) * 2) = val;
        }
    }
}

// ---------------- bf16 GEMM (Wo projection), fp32 out ------------------------
__global__ __launch_bounds__(256, 2) void k_gemm_bt(
    const u16* __restrict__ A, const u16* __restrict__ Bw,
    const float* __restrict__ bias, float* __restrict__ Cf,
    int M, int N, int K) {
    __shared__ u16 lA[128 * 64];
    __shared__ u16 lB[128 * 64];
    const int tid = threadIdx.x;
    const int l = tid & 63, w = tid >> 6;
    const int lr = l & 15, lk = l >> 4;
    const int wr = w >> 1, wc = w & 1;
    const int nbn = N >> 7;
    const int cpx = (int)gridDim.x >> 3;
    const int wg = (blockIdx.x & 7) * cpx + (blockIdx.x >> 3);
    const int bm = wg / nbn, bn = wg % nbn;

    long abase[4], bbase[4];
    int ldst[4];
#pragma unroll
    for (int t = 0; t < 4; ++t) {
        int c = t * 256 + tid;
        int p = c * 16;
        int row = p >> 7;
        int inrow = p & 127;
        int src = inrow ^ ((row & 7) << 4);
        ldst[t] = p;
        abase[t] = (long)(bm * 128 + row) * (K * 2) + src;
        bbase[t] = (long)(bn * 128 + row) * (K * 2) + src;
    }
    const int swz = (lr & 7) << 4;
    int aoff[4][2], boff[4][2];
#pragma unroll
    for (int m = 0; m < 4; ++m)
#pragma unroll
        for (int kc = 0; kc < 2; ++kc) {
            aoff[m][kc] = (wr * 64 + m * 16 + lr) * 128 + ((kc * 64 + lk * 16) ^ swz);
            boff[m][kc] = (wc * 64 + m * 16 + lr) * 128 + ((kc * 64 + lk * 16) ^ swz);
        }

    f32x4 acc[4][4] = {};
    const char* gA = (const char*)A;
    const char* gB = (const char*)Bw;
    const char* lAb = (const char*)lA;
    const char* lBb = (const char*)lB;
    const int nkt = K >> 6;
    for (int kt = 0; kt < nkt; ++kt) {
        __syncthreads();
#pragma unroll
        for (int t = 0; t < 4; ++t)
            gload16(gA + abase[t] + kt * 128, (char*)lA + ldst[t]);
#pragma unroll
        for (int t = 0; t < 4; ++t)
            gload16(gB + bbase[t] + kt * 128, (char*)lB + ldst[t]);
        __syncthreads();
#pragma unroll
        for (int kc = 0; kc < 2; ++kc) {
            bf16x8 av[4], bv[4];
#pragma unroll
            for (int m = 0; m < 4; ++m) av[m] = *(const bf16x8*)(lAb + aoff[m][kc]);
#pragma unroll
            for (int n = 0; n < 4; ++n) bv[n] = *(const bf16x8*)(lBb + boff[n][kc]);
#pragma unroll
            for (int m = 0; m < 4; ++m)
#pragma unroll
                for (int n = 0; n < 4; ++n)
                    acc[m][n] = __builtin_amdgcn_mfma_f32_16x16x32_bf16(av[m], bv[n], acc[m][n], 0, 0, 0);
        }
    }

    const int row0 = bm * 128 + wr * 64;
    const int col0 = bn * 128 + wc * 64;
    float bval[4];
#pragma unroll
    for (int n = 0; n < 4; ++n) bval[n] = bias[col0 + n * 16 + lr];
#pragma unroll
    for (int m = 0; m < 4; ++m)
#pragma unroll
        for (int j = 0; j < 4; ++j) {
            int row = row0 + m * 16 + lk * 4 + j;
#pragma unroll
            for (int n = 0; n < 4; ++n)
                Cf[(long)row * N + col0 + n * 16 + lr] = acc[m][n][j] + bval[n];
        }
}

// ---------------- flash attention v5: V^T pre-transposed in global -----------
__global__ __launch_bounds__(512, 4) void k_attn5(
    const u16* __restrict__ Qb, const u16* __restrict__ Kb,
    const u16* __restrict__ VTb, u16* __restrict__ Ob) {
    constexpr int T = 2048, D = 1024;
    constexpr int NT = T / 64;
    __shared__ u16 sK[2][4096];
    __shared__ u16 sV[2][4096];
    const int tid = threadIdx.x;
    const int l = tid & 63, w = tid >> 6;
    const int hi = l >> 5;
    const int q32 = l & 31;
    const int hi16 = hi * 16;
    const int kswz = (q32 & 7) << 4;
    const int bid = blockIdx.x;
    const int bh = (bid & 7) * 8 + ((bid >> 3) & 7);
    const int qt = bid >> 6;
    const int b = bh >> 4, h = bh & 15;

    const char* Qg = (const char*)(Qb + (long)b * T * D + h * 64);
    const char* Kg = (const char*)(Kb + (long)b * T * D + h * 64);
    const char* VTg = (const char*)(VTb + (long)bh * 64 * 2048);
    const int q0 = qt * 256 + w * 32;

    bf16x8 qf[4];
#pragma unroll
    for (int c = 0; c < 4; ++c)
        qf[c] = *(const bf16x8*)(Qg + (long)(q0 + q32) * 2048 + c * 32 + hi16);

    const int srow = tid >> 3;
    const int ssrc = ((tid & 7) * 16) ^ ((srow & 7) << 4);
    const int sdst = tid * 16;
    const long kbase = (long)srow * 2048 + ssrc;
    const long vbase = (long)srow * 4096 + ssrc;

    union { u16 s[8]; bf16x8 v; } ones_u;
#pragma unroll
    for (int i = 0; i < 8; ++i) ones_u.s[i] = 0x3F80;
    const bf16x8 onesv = ones_u.v;

#define STAGE(kt_, buf_) do {                                                  \
        gload16(Kg + (long)(kt_) * 64 * 2048 + kbase, (char*)sK[buf_] + sdst); \
        gload16(VTg + (kt_) * 128 + vbase, (char*)sV[buf_] + sdst);            \
    } while (0)

    STAGE(0, 0);
    __syncthreads();

    f32x16 o[2] = {};
    f32x16 lacc = {};
    float m = -1e30f;
    const float k1 = 0.18033688f;
    const float THR = 44.3616f;

    for (int kt = 0; kt < NT; ++kt) {
        if (kt + 1 < NT) STAGE(kt + 1, (kt + 1) & 1);

        const char* kbp = (const char*)sK[kt & 1];
        f32x16 st[2] = {};
        __builtin_amdgcn_s_setprio(1);
#pragma unroll
        for (int c = 0; c < 4; ++c) {
            bf16x8 kf = *(const bf16x8*)(kbp + q32 * 128 + ((c * 32 + hi16) ^ kswz));
            st[0] = __builtin_amdgcn_mfma_f32_32x32x16_bf16(kf, qf[c], st[0], 0, 0, 0);
        }
#pragma unroll
        for (int c = 0; c < 4; ++c) {
            bf16x8 kf = *(const bf16x8*)(kbp + (32 + q32) * 128 + ((c * 32 + hi16) ^ kswz));
            st[1] = __builtin_amdgcn_mfma_f32_32x32x16_bf16(kf, qf[c], st[1], 0, 0, 0);
        }
        __builtin_amdgcn_s_setprio(0);

        float t0 = max3f(st[0][0], st[0][1], st[0][2]);
        float t1 = max3f(st[0][3], st[0][4], st[0][5]);
        float t2 = max3f(st[0][6], st[0][7], st[0][8]);
        float t3 = max3f(st[0][9], st[0][10], st[0][11]);
        float t4 = max3f(st[0][12], st[0][13], st[0][14]);
        float t5 = max3f(st[1][0], st[1][1], st[1][2]);
        float t6 = max3f(st[1][3], st[1][4], st[1][5]);
        float t7 = max3f(st[1][6], st[1][7], st[1][8]);
        float t8 = max3f(st[1][9], st[1][10], st[1][11]);
        float t9 = max3f(st[1][12], st[1][13], st[1][14]);
        float u0 = max3f(t0, t1, t2);
        float u1 = max3f(t3, t4, st[0][15]);
        float u2 = max3f(t5, t6, t7);
        float u3 = max3f(t8, t9, st[1][15]);
        float rm = fmaxf(max3f(u0, u1, u2), u3);

        bool defer = __all(rm <= m + THR);
        if (!defer) {
            float rmw = fmaxf(rm, __shfl_xor(rm, 32));
            float mn = fmaxf(m, rmw);
            float aq = fexp2((m - mn) * k1);
            m = mn;
#pragma unroll
            for (int r = 0; r < 16; ++r) {
                int src = (r & 3) + 8 * (r >> 2) + 4 * hi;
                float ar = __shfl(aq, src);
                o[0][r] *= ar;
                o[1][r] *= ar;
                lacc[r] *= ar;
            }
        }
        float mk = m * k1;
#pragma unroll
        for (int n = 0; n < 2; ++n)
#pragma unroll
            for (int r = 0; r < 16; ++r)
                st[n][r] = fexp2(fmaf(st[n][r], k1, -mk));

        const char* vbp = (const char*)sV[kt & 1];
        __builtin_amdgcn_s_setprio(1);
#pragma unroll
        for (int c = 0; c < 4; ++c) {
            const int n = c >> 1, rb = (c & 1) * 8;
            uint A0 = cvtpk(st[n][rb + 0], st[n][rb + 1]);
            uint A1 = cvtpk(st[n][rb + 2], st[n][rb + 3]);
            uint B0 = cvtpk(st[n][rb + 4], st[n][rb + 5]);
            uint B1 = cvtpk(st[n][rb + 6], st[n][rb + 7]);
            plswap(A0, B0);
            plswap(A1, B1);
            union { uint u[4]; bf16x8 v; } pa;
            pa.u[0] = A0; pa.u[1] = A1; pa.u[2] = B0; pa.u[3] = B1;
            int cb = c * 32 + hi16;
            bf16x8 v0 = *(const bf16x8*)(vbp + q32 * 128 + (cb ^ kswz));
            bf16x8 v1 = *(const bf16x8*)(vbp + (32 + q32) * 128 + (cb ^ kswz));
            o[0] = __builtin_amdgcn_mfma_f32_32x32x16_bf16(pa.v, v0, o[0], 0, 0, 0);
            o[1] = __builtin_amdgcn_mfma_f32_32x32x16_bf16(pa.v, v1, o[1], 0, 0, 0);
            lacc  = __builtin_amdgcn_mfma_f32_32x32x16_bf16(pa.v, onesv, lacc, 0, 0, 0);
        }
        __builtin_amdgcn_s_setprio(0);
        __syncthreads();
    }
#undef STAGE

#pragma unroll
    for (int r = 0; r < 16; ++r) {
        float inv = 1.f / lacc[r];
        int srcq = (r & 3) + 8 * (r >> 2) + 4 * hi;
        int trow = q0 + srcq;
        char* orow = (char*)Ob + ((long)(b * T + trow) * D + h * 64) * 2;
        *(u16*)(orow + q32 * 2) = f2bf(o[0][r] * inv);
        *(u16*)(orow + (32 + q32) * 2) = f2bf(o[1][r] * inv);
    }
}

// ---------------------------------------------------------------------------
extern "C" void kernel_launch(void* const* d_in, const int* in_sizes, int n_in,
                              void* d_out, int out_size, void* d_ws, size_t ws_size,
                              hipStream_t stream) {
    const float* q  = (const float*)d_in[0];
    const float* k  = (const float*)d_in[1];
    const float* v  = (const float*)d_in[2];
    const float* Wq = (const float*)d_in[3];
    const float* bq = (const float*)d_in[4];
    const float* Wk = (const float*)d_in[5];
    const float* bk = (const float*)d_in[6];
    const float* Wv = (const float*)d_in[7];
    const float* bv = (const float*)d_in[8];
    const float* Wo = (const float*)d_in[9];
    const float* bo = (const float*)d_in[10];

    const long MT = 8192L * 1024;
    const long WT = 1024L * 1024;
    u16* ws   = (u16*)d_ws;
    u16* wall = ws;                    // Wq|Wk|Wv|Wo bf16, stacked
    u16* qbf  = wall + 4 * WT;         // Q|K row-major outputs
    u16* kbf  = qbf + MT;
    u16* vtb  = kbf + MT;              // V^T [bh][dh][t]
    u16* abf  = vtb + MT;              // attention output

    k_wconv<<<dim3(2048), dim3(256), 0, stream>>>(Wq, Wk, Wv, Wo, wall);

    k_gemm_qkv<<<dim3(1536), dim3(256), 0, stream>>>(q, k, v, wall,
                                                     bq, bk, bv, qbf, vtb);

    k_attn5<<<dim3(512), dim3(512), 0, stream>>>(qbf, kbf, vtb, abf);

    k_gemm_bt<<<dim3(512), dim3(256), 0, stream>>>(abf, wall + 3 * WT, bo,
                                                   (float*)d_out, 8192, 1024, 1024);
}